// Round 4
// baseline (1046.921 us; speedup 1.0000x reference)
//
#include <hip/hip_runtime.h>
#include <hip/hip_bf16.h>

// Problem constants: B=2, T=2048, C=1024, H=16, D=64
#define BB 2
#define TT 2048
#define CC 1024
#define HH 16
#define DD 64
#define MM (BB*TT)   // 4096

typedef float f32x4 __attribute__((ext_vector_type(4)));
typedef __bf16 bf16x8 __attribute__((ext_vector_type(8)));
typedef unsigned int u32x4 __attribute__((ext_vector_type(4)));

__device__ __forceinline__ unsigned short f2bf(float f) {
    unsigned int u = __float_as_uint(f);
    u += 0x7fff + ((u >> 16) & 1);          // round-to-nearest-even
    return (unsigned short)(u >> 16);
}
__device__ __forceinline__ unsigned int pk2(float a, float b) {
    return (unsigned int)f2bf(a) | ((unsigned int)f2bf(b) << 16);
}

// ---------------------------------------------------------------------------
// Kernel 0: fp32 -> bf16 elementwise (x). 8 elems/thread, exact cover.
// ---------------------------------------------------------------------------
__global__ __launch_bounds__(256) void cvt_f32_bf16(
    const float* __restrict__ in, unsigned short* __restrict__ out)
{
    const size_t i = (size_t)blockIdx.x * 256 + threadIdx.x;  // unit of 8 elems
    const float4* in4 = (const float4*)in;
    float4 a = in4[2 * i], b = in4[2 * i + 1];
    u32x4 o;
    o[0] = pk2(a.x, a.y); o[1] = pk2(a.z, a.w);
    o[2] = pk2(b.x, b.y); o[3] = pk2(b.z, b.w);
    *(u32x4*)(out + 8 * i) = o;
}

// ---------------------------------------------------------------------------
// Kernel 1: W [1024(k)][1024(n)] fp32 -> W_t bf16 [1024(n)][1024(k)].
// 64x64 LDS-tiled transpose. grid (16 n-tiles, 16 k-tiles, 4 matrices).
// ---------------------------------------------------------------------------
__global__ __launch_bounds__(256) void wtrans_kernel(
    const float* __restrict__ W0, const float* __restrict__ W1,
    const float* __restrict__ W2, const float* __restrict__ W3,
    unsigned short* __restrict__ wt)
{
    const int tid = threadIdx.x;
    const int n0 = blockIdx.x * 64;
    const int k0 = blockIdx.y * 64;
    const int which = blockIdx.z;
    const float* W = (which == 0) ? W0 : (which == 1) ? W1 : (which == 2) ? W2 : W3;

    __shared__ float t_lds[64][68];

    #pragma unroll
    for (int p = 0; p < 4; ++p) {
        int idx = tid + p * 256;         // 0..1023
        int r   = idx >> 4;              // 0..63 (k-row)
        int c4  = (idx & 15) * 4;        // 0..60 (n-col)
        *(float4*)&t_lds[r][c4] = *(const float4*)(W + (size_t)(k0 + r) * CC + n0 + c4);
    }
    __syncthreads();

    const int nl = tid >> 2;             // 0..63 local n
    const int ks = (tid & 3) * 16;       // 0,16,32,48 local k base
    unsigned int w[8];
    #pragma unroll
    for (int j = 0; j < 8; ++j)
        w[j] = pk2(t_lds[ks + 2 * j][nl], t_lds[ks + 2 * j + 1][nl]);
    unsigned short* dst = wt + (size_t)which * CC * CC + (size_t)(n0 + nl) * CC + k0 + ks;
    u32x4 o0; o0[0] = w[0]; o0[1] = w[1]; o0[2] = w[2]; o0[3] = w[3];
    u32x4 o1; o1[0] = w[4]; o1[1] = w[5]; o1[2] = w[6]; o1[3] = w[7];
    *(u32x4*)dst = o0;
    *(u32x4*)(dst + 8) = o1;
}

// ---------------------------------------------------------------------------
// Kernel 2: QKV MFMA GEMM.  C[4096, 3072] = x_bf[4096,1024] @ [Wq|Wk|Wv]^T
// B operand given transposed: wt[n][k]. Tile 128x128, BK=32, 4 waves,
// 4x4 16x16x32 fragments per wave. Epilogue: +bias, fp32 scatter to [B,H,T,D].
// ---------------------------------------------------------------------------
__global__ __launch_bounds__(256) void gemm_qkv_mfma(
    const unsigned short* __restrict__ xbf, const unsigned short* __restrict__ wt,
    const float* __restrict__ bq, const float* __restrict__ bk, const float* __restrict__ bv,
    float* __restrict__ qout, float* __restrict__ kout, float* __restrict__ vout)
{
    const int tid = threadIdx.x;
    const int m0 = blockIdx.y * 128;
    const int nc0 = blockIdx.x * 128;        // within concat 3072
    const int which = nc0 >> 10;             // 0=q 1=k 2=v (128 | 1024)
    const int cb = nc0 & 1023;               // col base within this projection
    const unsigned short* Bt = wt + (size_t)which * CC * CC;
    const float* bias = (which == 0) ? bq : (which == 1) ? bk : bv;
    float* outbuf = (which == 0) ? qout : (which == 1) ? kout : vout;

    // padded rows: 40 bf16 = 80 B -> 2-way bank aliasing on b128 reads (free)
    __shared__ unsigned short lds_a[128][40];
    __shared__ unsigned short lds_b[128][40];

    const int lane = tid & 63;
    const int wv = tid >> 6;               // wave 0..3
    const int wm = (wv & 1) * 64;
    const int wn = (wv >> 1) * 64;
    const int fr = lane & 15;              // fragment row/col
    const int ks = lane >> 4;              // k-slot (8 elems each)

    f32x4 acc[4][4];
    #pragma unroll
    for (int i = 0; i < 4; ++i)
        #pragma unroll
        for (int j = 0; j < 4; ++j) { acc[i][j][0]=0.f; acc[i][j][1]=0.f; acc[i][j][2]=0.f; acc[i][j][3]=0.f; }

    for (int k0 = 0; k0 < CC; k0 += 32) {
        __syncthreads();
        // stage: 512 chunks of 16B per tile; thread does 2 chunks each for A and B
        #pragma unroll
        for (int p = 0; p < 2; ++p) {
            int c = tid + p * 256;
            int row = c >> 2, slot = c & 3;
            *(u32x4*)&lds_a[row][slot * 8] =
                *(const u32x4*)(xbf + (size_t)(m0 + row) * CC + k0 + slot * 8);
            *(u32x4*)&lds_b[row][slot * 8] =
                *(const u32x4*)(Bt + (size_t)(cb + row) * CC + k0 + slot * 8);
        }
        __syncthreads();

        bf16x8 af[4], bfv[4];
        #pragma unroll
        for (int i = 0; i < 4; ++i) {
            af[i]  = __builtin_bit_cast(bf16x8, *(const u32x4*)&lds_a[wm + i * 16 + fr][ks * 8]);
            bfv[i] = __builtin_bit_cast(bf16x8, *(const u32x4*)&lds_b[wn + i * 16 + fr][ks * 8]);
        }
        #pragma unroll
        for (int mi = 0; mi < 4; ++mi)
            #pragma unroll
            for (int ni = 0; ni < 4; ++ni)
                acc[mi][ni] = __builtin_amdgcn_mfma_f32_16x16x32_bf16(af[mi], bfv[ni], acc[mi][ni], 0, 0, 0);
    }

    // epilogue: C[m][c] ; m = m0+wm+mi*16+ks*4+j ; c = cb+wn+ni*16+fr
    #pragma unroll
    for (int ni = 0; ni < 4; ++ni) {
        const int c = cb + wn + ni * 16 + fr;
        const float bv2 = bias[c];
        const int h = c >> 6, d = c & 63;
        #pragma unroll
        for (int mi = 0; mi < 4; ++mi) {
            #pragma unroll
            for (int j = 0; j < 4; ++j) {
                const int m = m0 + wm + mi * 16 + ks * 4 + j;
                const int b = m >> 11, t = m & 2047;
                outbuf[(((size_t)(b * HH + h) * TT + t) * DD) + d] = acc[mi][ni][j] + bv2;
            }
        }
    }
}

// ---------------------------------------------------------------------------
// Kernel 3: causal flash attention, fp32 (unchanged math).
// Only the final store now emits bf16 (feeds the out-proj MFMA GEMM).
// ---------------------------------------------------------------------------
__global__ __launch_bounds__(256) void attn_kernel(
    const float* __restrict__ q, const float* __restrict__ k,
    const float* __restrict__ v, unsigned short* __restrict__ ybf)
{
    const int tid = threadIdx.x;
    const int r   = tid >> 2;    // 0..63
    const int j   = tid & 3;     // 0..3
    const int qi  = (int)(gridDim.x - 1) - (int)blockIdx.x;  // heavy tiles first
    const int h   = blockIdx.y;
    const int bb  = blockIdx.z;
    const int q0  = qi * 64;
    const size_t headoff = (size_t)(bb * HH + h) * TT * DD;

    __shared__ float k_lds[64][68];
    __shared__ float v_lds[64][68];
    __shared__ float p_lds[64][68];

    float4 qreg[16];
    {
        const float4* qrow = (const float4*)(q + headoff + (size_t)(q0 + r) * DD);
        #pragma unroll
        for (int d4 = 0; d4 < 16; ++d4) {
            float4 t = qrow[d4];
            qreg[d4].x = t.x * 0.125f; qreg[d4].y = t.y * 0.125f;
            qreg[d4].z = t.z * 0.125f; qreg[d4].w = t.w * 0.125f;
        }
    }

    float m_i = -1e30f, l_i = 0.0f;
    float4 o_acc[4];
    #pragma unroll
    for (int dd = 0; dd < 4; ++dd) { o_acc[dd].x = 0.f; o_acc[dd].y = 0.f; o_acc[dd].z = 0.f; o_acc[dd].w = 0.f; }

    const int ntiles = qi + 1;
    for (int ti = 0; ti < ntiles; ++ti) {
        const int s0 = ti * 64;
        __syncthreads();
        #pragma unroll
        for (int p = 0; p < 4; ++p) {
            int idx  = tid + p * 256;
            int row  = idx >> 4;
            int col4 = (idx & 15) * 4;
            *(float4*)&k_lds[row][col4] =
                *(const float4*)(k + headoff + (size_t)(s0 + row) * DD + col4);
            *(float4*)&v_lds[row][col4] =
                *(const float4*)(v + headoff + (size_t)(s0 + row) * DD + col4);
        }
        __syncthreads();

        float sc[16];
        const bool diag = (s0 == q0);
        #pragma unroll
        for (int si = 0; si < 16; ++si) {
            const int s = si * 4 + j;
            float ax = 0.f, ay = 0.f, az = 0.f, aw = 0.f;
            #pragma unroll
            for (int d4 = 0; d4 < 16; ++d4) {
                float4 kv = *(const float4*)&k_lds[s][d4 * 4];
                ax += qreg[d4].x * kv.x; ay += qreg[d4].y * kv.y;
                az += qreg[d4].z * kv.z; aw += qreg[d4].w * kv.w;
            }
            float sval = (ax + ay) + (az + aw);
            if (diag && s > r) sval = -1e30f;
            sc[si] = sval;
        }

        float tmax = sc[0];
        #pragma unroll
        for (int si = 1; si < 16; ++si) tmax = fmaxf(tmax, sc[si]);
        tmax = fmaxf(tmax, __shfl_xor(tmax, 1));
        tmax = fmaxf(tmax, __shfl_xor(tmax, 2));
        const float m_new = fmaxf(m_i, tmax);
        const float alpha = __expf(m_i - m_new);
        float lsum = 0.f;
        #pragma unroll
        for (int si = 0; si < 16; ++si) {
            float pv = __expf(sc[si] - m_new);
            sc[si] = pv;
            lsum += pv;
        }
        lsum += __shfl_xor(lsum, 1);
        lsum += __shfl_xor(lsum, 2);
        l_i = l_i * alpha + lsum;
        m_i = m_new;
        #pragma unroll
        for (int dd = 0; dd < 4; ++dd) {
            o_acc[dd].x *= alpha; o_acc[dd].y *= alpha;
            o_acc[dd].z *= alpha; o_acc[dd].w *= alpha;
        }
        #pragma unroll
        for (int si = 0; si < 16; ++si) p_lds[r][si * 4 + j] = sc[si];
        __syncthreads();

        for (int s = 0; s < 64; ++s) {
            const float pv = p_lds[r][s];
            #pragma unroll
            for (int dd = 0; dd < 4; ++dd) {
                float4 vv = *(const float4*)&v_lds[s][j * 16 + dd * 4];
                o_acc[dd].x += pv * vv.x; o_acc[dd].y += pv * vv.y;
                o_acc[dd].z += pv * vv.z; o_acc[dd].w += pv * vv.w;
            }
        }
    }

    const float inv = 1.0f / l_i;
    unsigned short* yrow = ybf + ((size_t)bb * TT + (q0 + r)) * CC + h * DD + j * 16;
    u32x4 o0, o1;
    o0[0] = pk2(o_acc[0].x * inv, o_acc[0].y * inv);
    o0[1] = pk2(o_acc[0].z * inv, o_acc[0].w * inv);
    o0[2] = pk2(o_acc[1].x * inv, o_acc[1].y * inv);
    o0[3] = pk2(o_acc[1].z * inv, o_acc[1].w * inv);
    o1[0] = pk2(o_acc[2].x * inv, o_acc[2].y * inv);
    o1[1] = pk2(o_acc[2].z * inv, o_acc[2].w * inv);
    o1[2] = pk2(o_acc[3].x * inv, o_acc[3].y * inv);
    o1[3] = pk2(o_acc[3].z * inv, o_acc[3].w * inv);
    *(u32x4*)yrow = o0;
    *(u32x4*)(yrow + 8) = o1;
}

// ---------------------------------------------------------------------------
// Kernel 4: out-proj MFMA GEMM. out[4096,1024] = y_bf @ Wo^T(+bo), fp32 out.
// ---------------------------------------------------------------------------
__global__ __launch_bounds__(256) void gemm_out_mfma(
    const unsigned short* __restrict__ ybf, const unsigned short* __restrict__ wt_o,
    const float* __restrict__ bo, float* __restrict__ out)
{
    const int tid = threadIdx.x;
    const int m0 = blockIdx.y * 128;
    const int n0 = blockIdx.x * 128;

    __shared__ unsigned short lds_a[128][40];
    __shared__ unsigned short lds_b[128][40];

    const int lane = tid & 63;
    const int wv = tid >> 6;
    const int wm = (wv & 1) * 64;
    const int wn = (wv >> 1) * 64;
    const int fr = lane & 15;
    const int ks = lane >> 4;

    f32x4 acc[4][4];
    #pragma unroll
    for (int i = 0; i < 4; ++i)
        #pragma unroll
        for (int j = 0; j < 4; ++j) { acc[i][j][0]=0.f; acc[i][j][1]=0.f; acc[i][j][2]=0.f; acc[i][j][3]=0.f; }

    for (int k0 = 0; k0 < CC; k0 += 32) {
        __syncthreads();
        #pragma unroll
        for (int p = 0; p < 2; ++p) {
            int c = tid + p * 256;
            int row = c >> 2, slot = c & 3;
            *(u32x4*)&lds_a[row][slot * 8] =
                *(const u32x4*)(ybf + (size_t)(m0 + row) * CC + k0 + slot * 8);
            *(u32x4*)&lds_b[row][slot * 8] =
                *(const u32x4*)(wt_o + (size_t)(n0 + row) * CC + k0 + slot * 8);
        }
        __syncthreads();

        bf16x8 af[4], bfv[4];
        #pragma unroll
        for (int i = 0; i < 4; ++i) {
            af[i]  = __builtin_bit_cast(bf16x8, *(const u32x4*)&lds_a[wm + i * 16 + fr][ks * 8]);
            bfv[i] = __builtin_bit_cast(bf16x8, *(const u32x4*)&lds_b[wn + i * 16 + fr][ks * 8]);
        }
        #pragma unroll
        for (int mi = 0; mi < 4; ++mi)
            #pragma unroll
            for (int ni = 0; ni < 4; ++ni)
                acc[mi][ni] = __builtin_amdgcn_mfma_f32_16x16x32_bf16(af[mi], bfv[ni], acc[mi][ni], 0, 0, 0);
    }

    #pragma unroll
    for (int ni = 0; ni < 4; ++ni) {
        const int n = n0 + wn + ni * 16 + fr;
        const float bv2 = bo[n];
        #pragma unroll
        for (int mi = 0; mi < 4; ++mi) {
            #pragma unroll
            for (int j = 0; j < 4; ++j) {
                const int m = m0 + wm + mi * 16 + ks * 4 + j;
                out[(size_t)m * CC + n] = acc[mi][ni][j] + bv2;
            }
        }
    }
}

// ---------------------------------------------------------------------------
extern "C" void kernel_launch(void* const* d_in, const int* in_sizes, int n_in,
                              void* d_out, int out_size, void* d_ws, size_t ws_size,
                              hipStream_t stream) {
    const float* x  = (const float*)d_in[0];
    // d_in[1] = mask (bool) — causal structure is known, ignored
    const float* Wq = (const float*)d_in[2];
    const float* bq = (const float*)d_in[3];
    const float* Wk = (const float*)d_in[4];
    const float* bk = (const float*)d_in[5];
    const float* Wv = (const float*)d_in[6];
    const float* bv = (const float*)d_in[7];
    const float* Wo = (const float*)d_in[8];
    const float* bo = (const float*)d_in[9];
    float* out = (float*)d_out;

    const size_t NE = (size_t)BB * HH * TT * DD;  // 4,194,304
    float* qbuf = (float*)d_ws;
    float* kbuf = qbuf + NE;
    float* vbuf = kbuf + NE;
    unsigned short* xbf = (unsigned short*)(vbuf + NE);
    unsigned short* ybf = xbf + NE;
    unsigned short* wt  = ybf + NE;               // 4 x 1024 x 1024 bf16

    // x -> bf16 (4M elems, 8/thread)
    cvt_f32_bf16<<<2048, 256, 0, stream>>>(x, xbf);
    // W -> transposed bf16 [n][k] for all four weight matrices
    wtrans_kernel<<<dim3(16, 16, 4), 256, 0, stream>>>(Wq, Wk, Wv, Wo, wt);
    // QKV projection (N = 3072 concat)
    gemm_qkv_mfma<<<dim3(24, 32), 256, 0, stream>>>(
        xbf, wt, bq, bk, bv, qbuf, kbuf, vbuf);
    // causal attention (fp32 core, bf16 store)
    attn_kernel<<<dim3(TT / 64, HH, BB), 256, 0, stream>>>(qbuf, kbuf, vbuf, ybf);
    // output projection
    gemm_out_mfma<<<dim3(8, 32), 256, 0, stream>>>(
        ybf, wt + (size_t)3 * CC * CC, bo, out);
}

// Round 5
// 296.027 us; speedup vs baseline: 3.5366x; 3.5366x over previous
//
#include <hip/hip_runtime.h>
#include <hip/hip_bf16.h>

// Problem constants: B=2, T=2048, C=1024, H=16, D=64
#define BB 2
#define TT 2048
#define CC 1024
#define HH 16
#define DD 64
#define MM (BB*TT)   // 4096

typedef float f32x4 __attribute__((ext_vector_type(4)));
typedef __bf16 bf16x8 __attribute__((ext_vector_type(8)));
typedef unsigned int u32x4 __attribute__((ext_vector_type(4)));
typedef unsigned int u32x2 __attribute__((ext_vector_type(2)));

__device__ __forceinline__ unsigned short f2bf(float f) {
    unsigned int u = __float_as_uint(f);
    u += 0x7fff + ((u >> 16) & 1);          // round-to-nearest-even
    return (unsigned short)(u >> 16);
}
__device__ __forceinline__ unsigned int pk2(float a, float b) {
    return (unsigned int)f2bf(a) | ((unsigned int)f2bf(b) << 16);
}

// ---------------------------------------------------------------------------
// Kernel 0: fp32 -> bf16 elementwise (x). 8 elems/thread, exact cover.
// ---------------------------------------------------------------------------
__global__ __launch_bounds__(256) void cvt_f32_bf16(
    const float* __restrict__ in, unsigned short* __restrict__ out)
{
    const size_t i = (size_t)blockIdx.x * 256 + threadIdx.x;  // unit of 8 elems
    const float4* in4 = (const float4*)in;
    float4 a = in4[2 * i], b = in4[2 * i + 1];
    u32x4 o;
    o[0] = pk2(a.x, a.y); o[1] = pk2(a.z, a.w);
    o[2] = pk2(b.x, b.y); o[3] = pk2(b.z, b.w);
    *(u32x4*)(out + 8 * i) = o;
}

// ---------------------------------------------------------------------------
// Kernel 1: W [1024(k)][1024(n)] fp32 -> W_t bf16 [1024(n)][1024(k)].
// ---------------------------------------------------------------------------
__global__ __launch_bounds__(256) void wtrans_kernel(
    const float* __restrict__ W0, const float* __restrict__ W1,
    const float* __restrict__ W2, const float* __restrict__ W3,
    unsigned short* __restrict__ wt)
{
    const int tid = threadIdx.x;
    const int n0 = blockIdx.x * 64;
    const int k0 = blockIdx.y * 64;
    const int which = blockIdx.z;
    const float* W = (which == 0) ? W0 : (which == 1) ? W1 : (which == 2) ? W2 : W3;

    __shared__ float t_lds[64][68];

    #pragma unroll
    for (int p = 0; p < 4; ++p) {
        int idx = tid + p * 256;
        int r   = idx >> 4;
        int c4  = (idx & 15) * 4;
        *(float4*)&t_lds[r][c4] = *(const float4*)(W + (size_t)(k0 + r) * CC + n0 + c4);
    }
    __syncthreads();

    const int nl = tid >> 2;
    const int ks = (tid & 3) * 16;
    unsigned int w[8];
    #pragma unroll
    for (int j = 0; j < 8; ++j)
        w[j] = pk2(t_lds[ks + 2 * j][nl], t_lds[ks + 2 * j + 1][nl]);
    unsigned short* dst = wt + (size_t)which * CC * CC + (size_t)(n0 + nl) * CC + k0 + ks;
    u32x4 o0; o0[0] = w[0]; o0[1] = w[1]; o0[2] = w[2]; o0[3] = w[3];
    u32x4 o1; o1[0] = w[4]; o1[1] = w[5]; o1[2] = w[6]; o1[3] = w[7];
    *(u32x4*)dst = o0;
    *(u32x4*)(dst + 8) = o1;
}

// ---------------------------------------------------------------------------
// Kernel 2: QKV MFMA GEMM. Epilogue now emits bf16:
//   Q -> qbf [B,H,T,D], pre-scaled by 1/sqrt(D)=0.125
//   K -> kbf [B,H,T,D]
//   V -> vtbf [B,H,D,T]  (transposed, so attn PV B-frags are contiguous)
// ---------------------------------------------------------------------------
__global__ __launch_bounds__(256) void gemm_qkv_mfma(
    const unsigned short* __restrict__ xbf, const unsigned short* __restrict__ wt,
    const float* __restrict__ bq, const float* __restrict__ bk, const float* __restrict__ bv,
    unsigned short* __restrict__ qbf, unsigned short* __restrict__ kbf,
    unsigned short* __restrict__ vtbf)
{
    const int tid = threadIdx.x;
    const int m0 = blockIdx.y * 128;
    const int nc0 = blockIdx.x * 128;        // within concat 3072
    const int which = nc0 >> 10;             // 0=q 1=k 2=v
    const int cb = nc0 & 1023;
    const unsigned short* Bt = wt + (size_t)which * CC * CC;
    const float* bias = (which == 0) ? bq : (which == 1) ? bk : bv;

    __shared__ unsigned short lds_a[128][40];
    __shared__ unsigned short lds_b[128][40];

    const int lane = tid & 63;
    const int wv = tid >> 6;
    const int wm = (wv & 1) * 64;
    const int wn = (wv >> 1) * 64;
    const int fr = lane & 15;
    const int ks = lane >> 4;

    f32x4 acc[4][4];
    #pragma unroll
    for (int i = 0; i < 4; ++i)
        #pragma unroll
        for (int j = 0; j < 4; ++j) { acc[i][j][0]=0.f; acc[i][j][1]=0.f; acc[i][j][2]=0.f; acc[i][j][3]=0.f; }

    for (int k0 = 0; k0 < CC; k0 += 32) {
        __syncthreads();
        #pragma unroll
        for (int p = 0; p < 2; ++p) {
            int c = tid + p * 256;
            int row = c >> 2, slot = c & 3;
            *(u32x4*)&lds_a[row][slot * 8] =
                *(const u32x4*)(xbf + (size_t)(m0 + row) * CC + k0 + slot * 8);
            *(u32x4*)&lds_b[row][slot * 8] =
                *(const u32x4*)(Bt + (size_t)(cb + row) * CC + k0 + slot * 8);
        }
        __syncthreads();

        bf16x8 af[4], bfv[4];
        #pragma unroll
        for (int i = 0; i < 4; ++i) {
            af[i]  = __builtin_bit_cast(bf16x8, *(const u32x4*)&lds_a[wm + i * 16 + fr][ks * 8]);
            bfv[i] = __builtin_bit_cast(bf16x8, *(const u32x4*)&lds_b[wn + i * 16 + fr][ks * 8]);
        }
        #pragma unroll
        for (int mi = 0; mi < 4; ++mi)
            #pragma unroll
            for (int ni = 0; ni < 4; ++ni)
                acc[mi][ni] = __builtin_amdgcn_mfma_f32_16x16x32_bf16(af[mi], bfv[ni], acc[mi][ni], 0, 0, 0);
    }

    // epilogue: m = m0+wm+mi*16+ks*4+j ; c = cb+wn+ni*16+fr
    #pragma unroll
    for (int ni = 0; ni < 4; ++ni) {
        const int c = cb + wn + ni * 16 + fr;
        const float bv2 = bias[c];
        const int h = c >> 6, d = c & 63;
        #pragma unroll
        for (int mi = 0; mi < 4; ++mi) {
            const int mb = m0 + wm + mi * 16 + ks * 4;
            const int b = mb >> 11, t = mb & 2047;
            if (which == 2) {
                // V^T: 4 consecutive t for fixed d -> one 8B store
                u32x2 pkd;
                pkd[0] = pk2(acc[mi][ni][0] + bv2, acc[mi][ni][1] + bv2);
                pkd[1] = pk2(acc[mi][ni][2] + bv2, acc[mi][ni][3] + bv2);
                *(u32x2*)(vtbf + (((size_t)(b * HH + h) * DD + d) * TT) + t) = pkd;
            } else {
                unsigned short* dst = (which == 0) ? qbf : kbf;
                const float scl = (which == 0) ? 0.125f : 1.0f;
                #pragma unroll
                for (int j = 0; j < 4; ++j)
                    dst[(((size_t)(b * HH + h) * TT + (t + j)) * DD) + d] =
                        f2bf((acc[mi][ni][j] + bv2) * scl);
            }
        }
    }
}

// ---------------------------------------------------------------------------
// Kernel 3: causal flash attention on MFMA (bf16 in, bf16 out).
// Block = 256 thr = 4 waves; wave w owns q-rows 16w..16w+15 of a 64-row tile.
// Per KV tile (64): QK^T (8 mfma), wave-parallel online softmax in C-frag
// layout, P->LDS bf16 (wave-private rows), PV (8 mfma).
// Fragment conventions identical to the HW-verified GEMM above.
// ---------------------------------------------------------------------------
__global__ __launch_bounds__(256) void attn_mfma(
    const unsigned short* __restrict__ qbf, const unsigned short* __restrict__ kbf,
    const unsigned short* __restrict__ vtbf, unsigned short* __restrict__ ybf)
{
    const int tid  = threadIdx.x;
    const int w    = tid >> 6;
    const int lane = tid & 63;
    const int g    = lane >> 4;    // 0..3
    const int i    = lane & 15;    // 0..15
    const int qi   = 31 - (int)blockIdx.x;   // heavy tiles first
    const int h    = blockIdx.y;
    const int b    = blockIdx.z;
    const int q0   = qi * 64;
    const size_t hq = (size_t)(b * HH + h) * TT * DD;  // q/k [T][D]
    const size_t hv = (size_t)(b * HH + h) * DD * TT;  // v^T [D][T]

    __shared__ __align__(16) unsigned short k_lds[64][72];
    __shared__ __align__(16) unsigned short vt_lds[64][72];
    __shared__ __align__(16) unsigned short p_lds[64][72];

    // Q fragments: A-frag rows = q0+16w+i, k(=d) = ks*32 + g*8 + j
    bf16x8 qf[2];
    {
        const unsigned short* qrow = qbf + hq + (size_t)(q0 + 16 * w + i) * DD + g * 8;
        qf[0] = __builtin_bit_cast(bf16x8, *(const u32x4*)qrow);
        qf[1] = __builtin_bit_cast(bf16x8, *(const u32x4*)(qrow + 32));
    }

    f32x4 o_acc[4];
    f32x4 m_i, l_i;
    #pragma unroll
    for (int ni = 0; ni < 4; ++ni) { o_acc[ni][0]=0.f; o_acc[ni][1]=0.f; o_acc[ni][2]=0.f; o_acc[ni][3]=0.f; }
    #pragma unroll
    for (int e = 0; e < 4; ++e) { m_i[e] = -1e30f; l_i[e] = 0.f; }

    for (int kk = 0; kk <= qi; ++kk) {
        const int s0 = kk * 64;
        __syncthreads();   // previous tile's LDS fully consumed
        // Stage K tile [64 s][64 d] and V^T tile [64 d][64 s]; 512 16B chunks each
        #pragma unroll
        for (int p = 0; p < 2; ++p) {
            int c = tid + p * 256;          // 0..511
            int row = c >> 3, slot = c & 7;
            *(u32x4*)&k_lds[row][slot * 8] =
                *(const u32x4*)(kbf + hq + (size_t)(s0 + row) * DD + slot * 8);
            *(u32x4*)&vt_lds[row][slot * 8] =
                *(const u32x4*)(vtbf + hv + (size_t)row * TT + s0 + slot * 8);
        }
        __syncthreads();

        // S = Q K^T : m=r(local16), n=s(local16 per ni), k=d
        f32x4 s_acc[4];
        #pragma unroll
        for (int ni = 0; ni < 4; ++ni) { s_acc[ni][0]=0.f; s_acc[ni][1]=0.f; s_acc[ni][2]=0.f; s_acc[ni][3]=0.f; }
        #pragma unroll
        for (int ks = 0; ks < 2; ++ks)
            #pragma unroll
            for (int ni = 0; ni < 4; ++ni) {
                bf16x8 kb = __builtin_bit_cast(bf16x8,
                    *(const u32x4*)&k_lds[ni * 16 + i][ks * 32 + g * 8]);
                s_acc[ni] = __builtin_amdgcn_mfma_f32_16x16x32_bf16(qf[ks], kb, s_acc[ni], 0, 0, 0);
            }

        if (kk == qi) {   // diagonal tile: mask s>r (local indices, s0==q0)
            #pragma unroll
            for (int ni = 0; ni < 4; ++ni)
                #pragma unroll
                for (int reg = 0; reg < 4; ++reg)
                    if (ni * 16 + i > 16 * w + 4 * g + reg) s_acc[ni][reg] = -1e30f;
        }

        // Online softmax. Row r=16w+4g+reg is spread over 16 lanes (i).
        f32x4 rmax = s_acc[0];
        #pragma unroll
        for (int ni = 1; ni < 4; ++ni)
            #pragma unroll
            for (int e = 0; e < 4; ++e) rmax[e] = fmaxf(rmax[e], s_acc[ni][e]);
        #pragma unroll
        for (int msk = 1; msk < 16; msk <<= 1)
            #pragma unroll
            for (int e = 0; e < 4; ++e) rmax[e] = fmaxf(rmax[e], __shfl_xor(rmax[e], msk));

        f32x4 m_new, alpha;
        #pragma unroll
        for (int e = 0; e < 4; ++e) {
            m_new[e] = fmaxf(m_i[e], rmax[e]);
            alpha[e] = __expf(m_i[e] - m_new[e]);
        }
        f32x4 rsum;
        #pragma unroll
        for (int e = 0; e < 4; ++e) rsum[e] = 0.f;
        #pragma unroll
        for (int ni = 0; ni < 4; ++ni)
            #pragma unroll
            for (int e = 0; e < 4; ++e) {
                float pv = __expf(s_acc[ni][e] - m_new[e]);
                s_acc[ni][e] = pv;
                rsum[e] += pv;
            }
        #pragma unroll
        for (int msk = 1; msk < 16; msk <<= 1)
            #pragma unroll
            for (int e = 0; e < 4; ++e) rsum[e] += __shfl_xor(rsum[e], msk);
        #pragma unroll
        for (int e = 0; e < 4; ++e) {
            l_i[e] = l_i[e] * alpha[e] + rsum[e];
            m_i[e] = m_new[e];
        }
        #pragma unroll
        for (int ni = 0; ni < 4; ++ni)
            #pragma unroll
            for (int e = 0; e < 4; ++e) o_acc[ni][e] *= alpha[e];

        // P -> LDS bf16 (rows 16w+4g+reg: wave-private, no barrier needed)
        #pragma unroll
        for (int ni = 0; ni < 4; ++ni)
            #pragma unroll
            for (int reg = 0; reg < 4; ++reg)
                p_lds[16 * w + 4 * g + reg][ni * 16 + i] = f2bf(s_acc[ni][reg]);

        // O += P V : m=r, n=d(per ni), k=s
        #pragma unroll
        for (int ks = 0; ks < 2; ++ks) {
            bf16x8 pa = __builtin_bit_cast(bf16x8,
                *(const u32x4*)&p_lds[16 * w + i][ks * 32 + g * 8]);
            #pragma unroll
            for (int ni = 0; ni < 4; ++ni) {
                bf16x8 vb = __builtin_bit_cast(bf16x8,
                    *(const u32x4*)&vt_lds[ni * 16 + i][ks * 32 + g * 8]);
                o_acc[ni] = __builtin_amdgcn_mfma_f32_16x16x32_bf16(pa, vb, o_acc[ni], 0, 0, 0);
            }
        }
    }

    // Finalize: y[b, q0+16w+4g+reg, h*64 + ni*16 + i] = o/l
    f32x4 inv;
    #pragma unroll
    for (int e = 0; e < 4; ++e) inv[e] = 1.0f / l_i[e];
    #pragma unroll
    for (int ni = 0; ni < 4; ++ni)
        #pragma unroll
        for (int reg = 0; reg < 4; ++reg)
            ybf[((size_t)b * TT + (q0 + 16 * w + 4 * g + reg)) * CC + h * DD + ni * 16 + i] =
                f2bf(o_acc[ni][reg] * inv[reg]);
}

// ---------------------------------------------------------------------------
// Kernel 4: out-proj MFMA GEMM. out[4096,1024] = y_bf @ Wo^T(+bo), fp32 out.
// ---------------------------------------------------------------------------
__global__ __launch_bounds__(256) void gemm_out_mfma(
    const unsigned short* __restrict__ ybf, const unsigned short* __restrict__ wt_o,
    const float* __restrict__ bo, float* __restrict__ out)
{
    const int tid = threadIdx.x;
    const int m0 = blockIdx.y * 128;
    const int n0 = blockIdx.x * 128;

    __shared__ unsigned short lds_a[128][40];
    __shared__ unsigned short lds_b[128][40];

    const int lane = tid & 63;
    const int wv = tid >> 6;
    const int wm = (wv & 1) * 64;
    const int wn = (wv >> 1) * 64;
    const int fr = lane & 15;
    const int ks = lane >> 4;

    f32x4 acc[4][4];
    #pragma unroll
    for (int i = 0; i < 4; ++i)
        #pragma unroll
        for (int j = 0; j < 4; ++j) { acc[i][j][0]=0.f; acc[i][j][1]=0.f; acc[i][j][2]=0.f; acc[i][j][3]=0.f; }

    for (int k0 = 0; k0 < CC; k0 += 32) {
        __syncthreads();
        #pragma unroll
        for (int p = 0; p < 2; ++p) {
            int c = tid + p * 256;
            int row = c >> 2, slot = c & 3;
            *(u32x4*)&lds_a[row][slot * 8] =
                *(const u32x4*)(ybf + (size_t)(m0 + row) * CC + k0 + slot * 8);
            *(u32x4*)&lds_b[row][slot * 8] =
                *(const u32x4*)(wt_o + (size_t)(n0 + row) * CC + k0 + slot * 8);
        }
        __syncthreads();

        bf16x8 af[4], bfv[4];
        #pragma unroll
        for (int i = 0; i < 4; ++i) {
            af[i]  = __builtin_bit_cast(bf16x8, *(const u32x4*)&lds_a[wm + i * 16 + fr][ks * 8]);
            bfv[i] = __builtin_bit_cast(bf16x8, *(const u32x4*)&lds_b[wn + i * 16 + fr][ks * 8]);
        }
        #pragma unroll
        for (int mi = 0; mi < 4; ++mi)
            #pragma unroll
            for (int ni = 0; ni < 4; ++ni)
                acc[mi][ni] = __builtin_amdgcn_mfma_f32_16x16x32_bf16(af[mi], bfv[ni], acc[mi][ni], 0, 0, 0);
    }

    #pragma unroll
    for (int ni = 0; ni < 4; ++ni) {
        const int n = n0 + wn + ni * 16 + fr;
        const float bv2 = bo[n];
        #pragma unroll
        for (int mi = 0; mi < 4; ++mi) {
            #pragma unroll
            for (int j = 0; j < 4; ++j) {
                const int m = m0 + wm + mi * 16 + ks * 4 + j;
                out[(size_t)m * CC + n] = acc[mi][ni][j] + bv2;
            }
        }
    }
}

// ---------------------------------------------------------------------------
extern "C" void kernel_launch(void* const* d_in, const int* in_sizes, int n_in,
                              void* d_out, int out_size, void* d_ws, size_t ws_size,
                              hipStream_t stream) {
    const float* x  = (const float*)d_in[0];
    // d_in[1] = mask (bool) — causal structure known, ignored
    const float* Wq = (const float*)d_in[2];
    const float* bq = (const float*)d_in[3];
    const float* Wk = (const float*)d_in[4];
    const float* bk = (const float*)d_in[5];
    const float* Wv = (const float*)d_in[6];
    const float* bv = (const float*)d_in[7];
    const float* Wo = (const float*)d_in[8];
    const float* bo = (const float*)d_in[9];
    float* out = (float*)d_out;

    const size_t NE = (size_t)MM * CC;            // 4,194,304
    unsigned short* xbf  = (unsigned short*)d_ws; // bf16 x
    unsigned short* ybf  = xbf + NE;              // bf16 attn out [B,T,C]
    unsigned short* wt   = ybf + NE;              // 4x 1024x1024 bf16 W^T
    unsigned short* qbf  = wt + (size_t)4 * CC * CC;
    unsigned short* kbf  = qbf + NE;
    unsigned short* vtbf = kbf + NE;

    cvt_f32_bf16<<<2048, 256, 0, stream>>>(x, xbf);
    wtrans_kernel<<<dim3(16, 16, 4), 256, 0, stream>>>(Wq, Wk, Wv, Wo, wt);
    gemm_qkv_mfma<<<dim3(24, 32), 256, 0, stream>>>(
        xbf, wt, bq, bk, bv, qbf, kbf, vtbf);
    attn_mfma<<<dim3(TT / 64, HH, BB), 256, 0, stream>>>(qbf, kbf, vtbf, ybf);
    gemm_out_mfma<<<dim3(8, 32), 256, 0, stream>>>(
        ybf, wt + (size_t)3 * CC * CC, bo, out);
}

// Round 7
// 273.468 us; speedup vs baseline: 3.8283x; 1.0825x over previous
//
#include <hip/hip_runtime.h>
#include <hip/hip_bf16.h>

// Problem constants: B=2, T=2048, C=1024, H=16, D=64
#define BB 2
#define TT 2048
#define CC 1024
#define HH 16
#define DD 64
#define MM (BB*TT)   // 4096

typedef float f32x4 __attribute__((ext_vector_type(4)));
typedef __bf16 bf16x8 __attribute__((ext_vector_type(8)));
typedef unsigned int u32x4 __attribute__((ext_vector_type(4)));
typedef unsigned int u32x2 __attribute__((ext_vector_type(2)));

__device__ __forceinline__ unsigned short f2bf(float f) {
    unsigned int u = __float_as_uint(f);
    u += 0x7fff + ((u >> 16) & 1);          // round-to-nearest-even
    return (unsigned short)(u >> 16);
}
__device__ __forceinline__ unsigned int pk2(float a, float b) {
    return (unsigned int)f2bf(a) | ((unsigned int)f2bf(b) << 16);
}

// global -> LDS direct 16B copy (wave-uniform LDS base + lane*16).
// AS casts via integer (CK pattern): low 32 bits of a generic LDS pointer
// are the LDS byte offset.
__device__ __forceinline__ void gload_lds16(const void* g, void* l) {
    __builtin_amdgcn_global_load_lds(
        (const __attribute__((address_space(1))) unsigned int*)(unsigned long long)g,
        (__attribute__((address_space(3))) unsigned int*)(unsigned int)(unsigned long long)l,
        16, 0, 0);
}

// ---------------------------------------------------------------------------
// Kernel 0: fp32 -> bf16 elementwise (x). 8 elems/thread, exact cover.
// ---------------------------------------------------------------------------
__global__ __launch_bounds__(256) void cvt_f32_bf16(
    const float* __restrict__ in, unsigned short* __restrict__ out)
{
    const size_t i = (size_t)blockIdx.x * 256 + threadIdx.x;  // unit of 8 elems
    const float4* in4 = (const float4*)in;
    float4 a = in4[2 * i], b = in4[2 * i + 1];
    u32x4 o;
    o[0] = pk2(a.x, a.y); o[1] = pk2(a.z, a.w);
    o[2] = pk2(b.x, b.y); o[3] = pk2(b.z, b.w);
    *(u32x4*)(out + 8 * i) = o;
}

// ---------------------------------------------------------------------------
// Kernel 1: W [1024(k)][1024(n)] fp32 -> W_t bf16 [1024(n)][1024(k)].
// ---------------------------------------------------------------------------
__global__ __launch_bounds__(256) void wtrans_kernel(
    const float* __restrict__ W0, const float* __restrict__ W1,
    const float* __restrict__ W2, const float* __restrict__ W3,
    unsigned short* __restrict__ wt)
{
    const int tid = threadIdx.x;
    const int n0 = blockIdx.x * 64;
    const int k0 = blockIdx.y * 64;
    const int which = blockIdx.z;
    const float* W = (which == 0) ? W0 : (which == 1) ? W1 : (which == 2) ? W2 : W3;

    __shared__ float t_lds[64][68];

    #pragma unroll
    for (int p = 0; p < 4; ++p) {
        int idx = tid + p * 256;
        int r   = idx >> 4;
        int c4  = (idx & 15) * 4;
        *(float4*)&t_lds[r][c4] = *(const float4*)(W + (size_t)(k0 + r) * CC + n0 + c4);
    }
    __syncthreads();

    const int nl = tid >> 2;
    const int ks = (tid & 3) * 16;
    unsigned int w[8];
    #pragma unroll
    for (int j = 0; j < 8; ++j)
        w[j] = pk2(t_lds[ks + 2 * j][nl], t_lds[ks + 2 * j + 1][nl]);
    unsigned short* dst = wt + (size_t)which * CC * CC + (size_t)(n0 + nl) * CC + k0 + ks;
    u32x4 o0; o0[0] = w[0]; o0[1] = w[1]; o0[2] = w[2]; o0[3] = w[3];
    u32x4 o1; o1[0] = w[4]; o1[1] = w[5]; o1[2] = w[6]; o1[3] = w[7];
    *(u32x4*)dst = o0;
    *(u32x4*)(dst + 8) = o1;
}

// ---------------------------------------------------------------------------
// Kernel 2: QKV MFMA GEMM, m97 structure (global_load_lds, linear LDS).
//   Q -> qbf [B,H,T,D] bf16, pre-scaled 0.125 ; K -> kbf [B,H,T,D] bf16
//   V -> vtbf [B,H,D,T] bf16 (transposed)
// ---------------------------------------------------------------------------
__global__ __launch_bounds__(256) void gemm_qkv_mfma(
    const unsigned short* __restrict__ xbf, const unsigned short* __restrict__ wt,
    const float* __restrict__ bq, const float* __restrict__ bk, const float* __restrict__ bv,
    unsigned short* __restrict__ qbf, unsigned short* __restrict__ kbf,
    unsigned short* __restrict__ vtbf)
{
    const int tid = threadIdx.x;
    const int m0 = blockIdx.y * 128;
    const int nc0 = blockIdx.x * 128;        // within concat 3072
    const int which = nc0 >> 10;             // 0=q 1=k 2=v
    const int cb = nc0 & 1023;
    const unsigned short* Bt = wt + (size_t)which * CC * CC;
    const float* bias = (which == 0) ? bq : (which == 1) ? bk : bv;

    __shared__ __align__(16) unsigned short lds_a[128][32];  // linear (m97)
    __shared__ __align__(16) unsigned short lds_b[128][32];

    const int lane = tid & 63;
    const int wv = tid >> 6;
    const int wm = (wv & 1) * 64;
    const int wn = (wv >> 1) * 64;
    const int fr = lane & 15;
    const int ks = lane >> 4;

    // staging geometry: wave wv stages segments {2wv, 2wv+1} (16 rows each)
    const int lrow = lane >> 2;          // 0..15 row within segment
    const int lcol = (lane & 3) * 8;     // 16B chunk within row (bf16 elems)

    f32x4 acc[4][4];
    #pragma unroll
    for (int i = 0; i < 4; ++i)
        #pragma unroll
        for (int j = 0; j < 4; ++j) { acc[i][j][0]=0.f; acc[i][j][1]=0.f; acc[i][j][2]=0.f; acc[i][j][3]=0.f; }

    for (int k0 = 0; k0 < CC; k0 += 32) {
        __syncthreads();
        #pragma unroll
        for (int c = 0; c < 2; ++c) {
            const int r0 = (wv * 2 + c) * 16;
            gload_lds16(xbf + (size_t)(m0 + r0 + lrow) * CC + k0 + lcol, &lds_a[r0][0]);
            gload_lds16(Bt  + (size_t)(cb + r0 + lrow) * CC + k0 + lcol, &lds_b[r0][0]);
        }
        __syncthreads();   // compiler emits vmcnt(0) drain here

        bf16x8 af[4], bfv[4];
        #pragma unroll
        for (int i = 0; i < 4; ++i) {
            af[i]  = __builtin_bit_cast(bf16x8, *(const u32x4*)&lds_a[wm + i * 16 + fr][ks * 8]);
            bfv[i] = __builtin_bit_cast(bf16x8, *(const u32x4*)&lds_b[wn + i * 16 + fr][ks * 8]);
        }
        #pragma unroll
        for (int mi = 0; mi < 4; ++mi)
            #pragma unroll
            for (int ni = 0; ni < 4; ++ni)
                acc[mi][ni] = __builtin_amdgcn_mfma_f32_16x16x32_bf16(af[mi], bfv[ni], acc[mi][ni], 0, 0, 0);
    }

    // epilogue (validated round 5): m = m0+wm+mi*16+ks*4+j ; c = cb+wn+ni*16+fr
    #pragma unroll
    for (int ni = 0; ni < 4; ++ni) {
        const int c = cb + wn + ni * 16 + fr;
        const float bv2 = bias[c];
        const int h = c >> 6, d = c & 63;
        #pragma unroll
        for (int mi = 0; mi < 4; ++mi) {
            const int mb = m0 + wm + mi * 16 + ks * 4;
            const int b = mb >> 11, t = mb & 2047;
            if (which == 2) {
                u32x2 pkd;
                pkd[0] = pk2(acc[mi][ni][0] + bv2, acc[mi][ni][1] + bv2);
                pkd[1] = pk2(acc[mi][ni][2] + bv2, acc[mi][ni][3] + bv2);
                *(u32x2*)(vtbf + (((size_t)(b * HH + h) * DD + d) * TT) + t) = pkd;
            } else {
                unsigned short* dst = (which == 0) ? qbf : kbf;
                const float scl = (which == 0) ? 0.125f : 1.0f;
                #pragma unroll
                for (int j = 0; j < 4; ++j)
                    dst[(((size_t)(b * HH + h) * TT + (t + j)) * DD) + d] =
                        f2bf((acc[mi][ni][j] + bv2) * scl);
            }
        }
    }
}

// ---------------------------------------------------------------------------
// Kernel 3: causal flash attention on MFMA. 512 thr = 8 waves; 128 q-rows
// per block (wave w owns rows 16w..16w+15); KVBLK=64; T14 reg-prefetch of
// the next K/V tile overlapped with compute. Fragment math identical to the
// HW-verified round-5 kernel.
// ---------------------------------------------------------------------------
__global__ __launch_bounds__(512) void attn_mfma(
    const unsigned short* __restrict__ qbf, const unsigned short* __restrict__ kbf,
    const unsigned short* __restrict__ vtbf, unsigned short* __restrict__ ybf)
{
    const int tid  = threadIdx.x;
    const int w    = tid >> 6;     // 0..7
    const int lane = tid & 63;
    const int g    = lane >> 4;    // 0..3
    const int i    = lane & 15;    // 0..15
    const int qi   = 15 - (int)blockIdx.x;   // heavy tiles first
    const int h    = blockIdx.y;
    const int b    = blockIdx.z;
    const int q0   = qi * 128;
    const size_t hq = (size_t)(b * HH + h) * TT * DD;  // q/k [T][D]
    const size_t hv = (size_t)(b * HH + h) * DD * TT;  // v^T [D][T]

    __shared__ __align__(16) unsigned short k_lds[64][72];
    __shared__ __align__(16) unsigned short vt_lds[64][72];
    __shared__ __align__(16) unsigned short p_lds[128][72];

    // Q fragments: A-frag rows = q0+16w+i, k(=d) = lks*32 + g*8 + j
    bf16x8 qf[2];
    {
        const unsigned short* qrow = qbf + hq + (size_t)(q0 + 16 * w + i) * DD + g * 8;
        qf[0] = __builtin_bit_cast(bf16x8, *(const u32x4*)qrow);
        qf[1] = __builtin_bit_cast(bf16x8, *(const u32x4*)(qrow + 32));
    }

    f32x4 o_acc[4];
    f32x4 m_i, l_i;
    #pragma unroll
    for (int ni = 0; ni < 4; ++ni) { o_acc[ni][0]=0.f; o_acc[ni][1]=0.f; o_acc[ni][2]=0.f; o_acc[ni][3]=0.f; }
    #pragma unroll
    for (int e = 0; e < 4; ++e) { m_i[e] = -1e30f; l_i[e] = 0.f; }

    // staging: 512 threads x one 16B chunk per matrix per tile
    const int srow  = tid >> 3;         // 0..63
    const int sslot = (tid & 7) * 8;    // bf16 elems

    const int nt = 2 * qi + 2;
    // prologue: prefetch tile 0 into registers
    u32x4 kreg = *(const u32x4*)(kbf + hq + (size_t)srow * DD + sslot);
    u32x4 vreg = *(const u32x4*)(vtbf + hv + (size_t)srow * TT + sslot);

    for (int kk = 0; kk < nt; ++kk) {
        __syncthreads();   // prev tile's LDS fully consumed
        *(u32x4*)&k_lds[srow][sslot]  = kreg;
        *(u32x4*)&vt_lds[srow][sslot] = vreg;
        __syncthreads();
        if (kk + 1 < nt) {   // issue next-tile loads; latency hides under compute
            const int s1 = (kk + 1) * 64;
            kreg = *(const u32x4*)(kbf + hq + (size_t)(s1 + srow) * DD + sslot);
            vreg = *(const u32x4*)(vtbf + hv + (size_t)srow * TT + s1 + sslot);
        }

        // last tile: waves 0..3 (rows < 64) are fully masked -> skip compute
        // (barriers above/below are still hit by all waves; p_lds rows are
        //  wave-private so no cross-wave hazard)
        if (kk == nt - 1 && w < 4) continue;

        const int s0 = kk * 64;
        // S = Q K^T
        f32x4 s_acc[4];
        #pragma unroll
        for (int ni = 0; ni < 4; ++ni) { s_acc[ni][0]=0.f; s_acc[ni][1]=0.f; s_acc[ni][2]=0.f; s_acc[ni][3]=0.f; }
        #pragma unroll
        for (int lks = 0; lks < 2; ++lks)
            #pragma unroll
            for (int ni = 0; ni < 4; ++ni) {
                bf16x8 kb = __builtin_bit_cast(bf16x8,
                    *(const u32x4*)&k_lds[ni * 16 + i][lks * 32 + g * 8]);
                s_acc[ni] = __builtin_amdgcn_mfma_f32_16x16x32_bf16(qf[lks], kb, s_acc[ni], 0, 0, 0);
            }

        if (kk >= 2 * qi) {   // diagonal zone: mask s_glob > r_glob
            const int r_glob = q0 + 16 * w + 4 * g;
            #pragma unroll
            for (int ni = 0; ni < 4; ++ni) {
                const int s_glob = s0 + ni * 16 + i;
                #pragma unroll
                for (int reg = 0; reg < 4; ++reg)
                    if (s_glob > r_glob + reg) s_acc[ni][reg] = -1e30f;
            }
        }

        // Online softmax (row r = 16w+4g+reg spread over 16 lanes)
        f32x4 rmax = s_acc[0];
        #pragma unroll
        for (int ni = 1; ni < 4; ++ni)
            #pragma unroll
            for (int e = 0; e < 4; ++e) rmax[e] = fmaxf(rmax[e], s_acc[ni][e]);
        #pragma unroll
        for (int msk = 1; msk < 16; msk <<= 1)
            #pragma unroll
            for (int e = 0; e < 4; ++e) rmax[e] = fmaxf(rmax[e], __shfl_xor(rmax[e], msk));

        f32x4 m_new, alpha;
        #pragma unroll
        for (int e = 0; e < 4; ++e) {
            m_new[e] = fmaxf(m_i[e], rmax[e]);
            alpha[e] = __expf(m_i[e] - m_new[e]);
        }
        f32x4 rsum;
        #pragma unroll
        for (int e = 0; e < 4; ++e) rsum[e] = 0.f;
        #pragma unroll
        for (int ni = 0; ni < 4; ++ni)
            #pragma unroll
            for (int e = 0; e < 4; ++e) {
                float pv = __expf(s_acc[ni][e] - m_new[e]);
                s_acc[ni][e] = pv;
                rsum[e] += pv;
            }
        #pragma unroll
        for (int msk = 1; msk < 16; msk <<= 1)
            #pragma unroll
            for (int e = 0; e < 4; ++e) rsum[e] += __shfl_xor(rsum[e], msk);
        #pragma unroll
        for (int e = 0; e < 4; ++e) {
            l_i[e] = l_i[e] * alpha[e] + rsum[e];
            m_i[e] = m_new[e];
        }
        #pragma unroll
        for (int ni = 0; ni < 4; ++ni)
            #pragma unroll
            for (int e = 0; e < 4; ++e) o_acc[ni][e] *= alpha[e];

        // P -> LDS bf16 (rows 16w+4g+reg: wave-private)
        #pragma unroll
        for (int ni = 0; ni < 4; ++ni)
            #pragma unroll
            for (int reg = 0; reg < 4; ++reg)
                p_lds[16 * w + 4 * g + reg][ni * 16 + i] = f2bf(s_acc[ni][reg]);

        // O += P V
        #pragma unroll
        for (int lks = 0; lks < 2; ++lks) {
            bf16x8 pa = __builtin_bit_cast(bf16x8,
                *(const u32x4*)&p_lds[16 * w + i][lks * 32 + g * 8]);
            #pragma unroll
            for (int ni = 0; ni < 4; ++ni) {
                bf16x8 vb = __builtin_bit_cast(bf16x8,
                    *(const u32x4*)&vt_lds[ni * 16 + i][lks * 32 + g * 8]);
                o_acc[ni] = __builtin_amdgcn_mfma_f32_16x16x32_bf16(pa, vb, o_acc[ni], 0, 0, 0);
            }
        }
    }

    // Finalize: y[b, q0+16w+4g+reg, h*64 + ni*16 + i] = o/l
    f32x4 inv;
    #pragma unroll
    for (int e = 0; e < 4; ++e) inv[e] = 1.0f / l_i[e];
    #pragma unroll
    for (int ni = 0; ni < 4; ++ni)
        #pragma unroll
        for (int reg = 0; reg < 4; ++reg)
            ybf[((size_t)b * TT + (q0 + 16 * w + 4 * g + reg)) * CC + h * DD + ni * 16 + i] =
                f2bf(o_acc[ni][reg] * inv[reg]);
}

// ---------------------------------------------------------------------------
// Kernel 4: out-proj MFMA GEMM (m97 structure). out = y_bf @ Wo^T + bo, fp32.
// ---------------------------------------------------------------------------
__global__ __launch_bounds__(256) void gemm_out_mfma(
    const unsigned short* __restrict__ ybf, const unsigned short* __restrict__ wt_o,
    const float* __restrict__ bo, float* __restrict__ out)
{
    const int tid = threadIdx.x;
    const int m0 = blockIdx.y * 128;
    const int n0 = blockIdx.x * 128;

    __shared__ __align__(16) unsigned short lds_a[128][32];
    __shared__ __align__(16) unsigned short lds_b[128][32];

    const int lane = tid & 63;
    const int wv = tid >> 6;
    const int wm = (wv & 1) * 64;
    const int wn = (wv >> 1) * 64;
    const int fr = lane & 15;
    const int ks = lane >> 4;
    const int lrow = lane >> 2;
    const int lcol = (lane & 3) * 8;

    f32x4 acc[4][4];
    #pragma unroll
    for (int i = 0; i < 4; ++i)
        #pragma unroll
        for (int j = 0; j < 4; ++j) { acc[i][j][0]=0.f; acc[i][j][1]=0.f; acc[i][j][2]=0.f; acc[i][j][3]=0.f; }

    for (int k0 = 0; k0 < CC; k0 += 32) {
        __syncthreads();
        #pragma unroll
        for (int c = 0; c < 2; ++c) {
            const int r0 = (wv * 2 + c) * 16;
            gload_lds16(ybf  + (size_t)(m0 + r0 + lrow) * CC + k0 + lcol, &lds_a[r0][0]);
            gload_lds16(wt_o + (size_t)(n0 + r0 + lrow) * CC + k0 + lcol, &lds_b[r0][0]);
        }
        __syncthreads();

        bf16x8 af[4], bfv[4];
        #pragma unroll
        for (int i = 0; i < 4; ++i) {
            af[i]  = __builtin_bit_cast(bf16x8, *(const u32x4*)&lds_a[wm + i * 16 + fr][ks * 8]);
            bfv[i] = __builtin_bit_cast(bf16x8, *(const u32x4*)&lds_b[wn + i * 16 + fr][ks * 8]);
        }
        #pragma unroll
        for (int mi = 0; mi < 4; ++mi)
            #pragma unroll
            for (int ni = 0; ni < 4; ++ni)
                acc[mi][ni] = __builtin_amdgcn_mfma_f32_16x16x32_bf16(af[mi], bfv[ni], acc[mi][ni], 0, 0, 0);
    }

    #pragma unroll
    for (int ni = 0; ni < 4; ++ni) {
        const int n = n0 + wn + ni * 16 + fr;
        const float bv2 = bo[n];
        #pragma unroll
        for (int mi = 0; mi < 4; ++mi) {
            #pragma unroll
            for (int j = 0; j < 4; ++j) {
                const int m = m0 + wm + mi * 16 + ks * 4 + j;
                out[(size_t)m * CC + n] = acc[mi][ni][j] + bv2;
            }
        }
    }
}

// ---------------------------------------------------------------------------
extern "C" void kernel_launch(void* const* d_in, const int* in_sizes, int n_in,
                              void* d_out, int out_size, void* d_ws, size_t ws_size,
                              hipStream_t stream) {
    const float* x  = (const float*)d_in[0];
    // d_in[1] = mask (bool) — causal structure known, ignored
    const float* Wq = (const float*)d_in[2];
    const float* bq = (const float*)d_in[3];
    const float* Wk = (const float*)d_in[4];
    const float* bk = (const float*)d_in[5];
    const float* Wv = (const float*)d_in[6];
    const float* bv = (const float*)d_in[7];
    const float* Wo = (const float*)d_in[8];
    const float* bo = (const float*)d_in[9];
    float* out = (float*)d_out;

    const size_t NE = (size_t)MM * CC;            // 4,194,304
    unsigned short* xbf  = (unsigned short*)d_ws; // bf16 x
    unsigned short* ybf  = xbf + NE;              // bf16 attn out [B,T,C]
    unsigned short* wt   = ybf + NE;              // 4x 1024x1024 bf16 W^T
    unsigned short* qbf  = wt + (size_t)4 * CC * CC;
    unsigned short* kbf  = qbf + NE;
    unsigned short* vtbf = kbf + NE;

    cvt_f32_bf16<<<2048, 256, 0, stream>>>(x, xbf);
    wtrans_kernel<<<dim3(16, 16, 4), 256, 0, stream>>>(Wq, Wk, Wv, Wo, wt);
    gemm_qkv_mfma<<<dim3(24, 32), 256, 0, stream>>>(
        xbf, wt, bq, bk, bv, qbf, kbf, vtbf);
    attn_mfma<<<dim3(TT / 128, HH, BB), 512, 0, stream>>>(qbf, kbf, vtbf, ybf);
    gemm_out_mfma<<<dim3(8, 32), 256, 0, stream>>>(
        ybf, wt + (size_t)3 * CC * CC, bo, out);
}

// Round 8
// 271.535 us; speedup vs baseline: 3.8556x; 1.0071x over previous
//
#include <hip/hip_runtime.h>
#include <hip/hip_bf16.h>

// Problem constants: B=2, T=2048, C=1024, H=16, D=64
#define BB 2
#define TT 2048
#define CC 1024
#define HH 16
#define DD 64
#define MM (BB*TT)   // 4096

typedef float f32x4 __attribute__((ext_vector_type(4)));
typedef __bf16 bf16x8 __attribute__((ext_vector_type(8)));
typedef unsigned int u32x4 __attribute__((ext_vector_type(4)));
typedef unsigned int u32x2 __attribute__((ext_vector_type(2)));

__device__ __forceinline__ unsigned short f2bf(float f) {
    unsigned int u = __float_as_uint(f);
    u += 0x7fff + ((u >> 16) & 1);          // round-to-nearest-even
    return (unsigned short)(u >> 16);
}
__device__ __forceinline__ unsigned int pk2(float a, float b) {
    return (unsigned int)f2bf(a) | ((unsigned int)f2bf(b) << 16);
}

// global -> LDS direct 16B copy (wave-uniform LDS base + lane*16).
__device__ __forceinline__ void gload_lds16(const void* g, void* l) {
    __builtin_amdgcn_global_load_lds(
        (const __attribute__((address_space(1))) unsigned int*)(unsigned long long)g,
        (__attribute__((address_space(3))) unsigned int*)(unsigned int)(unsigned long long)l,
        16, 0, 0);
}

// ---------------------------------------------------------------------------
// Kernel 0: fp32 -> bf16 elementwise (x). 8 elems/thread, exact cover.
// ---------------------------------------------------------------------------
__global__ __launch_bounds__(256) void cvt_f32_bf16(
    const float* __restrict__ in, unsigned short* __restrict__ out)
{
    const size_t i = (size_t)blockIdx.x * 256 + threadIdx.x;  // unit of 8 elems
    const float4* in4 = (const float4*)in;
    float4 a = in4[2 * i], b = in4[2 * i + 1];
    u32x4 o;
    o[0] = pk2(a.x, a.y); o[1] = pk2(a.z, a.w);
    o[2] = pk2(b.x, b.y); o[3] = pk2(b.z, b.w);
    *(u32x4*)(out + 8 * i) = o;
}

// ---------------------------------------------------------------------------
// Kernel 1: W [1024(k)][1024(n)] fp32 -> W_t bf16 [1024(n)][1024(k)].
// ---------------------------------------------------------------------------
__global__ __launch_bounds__(256) void wtrans_kernel(
    const float* __restrict__ W0, const float* __restrict__ W1,
    const float* __restrict__ W2, const float* __restrict__ W3,
    unsigned short* __restrict__ wt)
{
    const int tid = threadIdx.x;
    const int n0 = blockIdx.x * 64;
    const int k0 = blockIdx.y * 64;
    const int which = blockIdx.z;
    const float* W = (which == 0) ? W0 : (which == 1) ? W1 : (which == 2) ? W2 : W3;

    __shared__ float t_lds[64][68];

    #pragma unroll
    for (int p = 0; p < 4; ++p) {
        int idx = tid + p * 256;
        int r   = idx >> 4;
        int c4  = (idx & 15) * 4;
        *(float4*)&t_lds[r][c4] = *(const float4*)(W + (size_t)(k0 + r) * CC + n0 + c4);
    }
    __syncthreads();

    const int nl = tid >> 2;
    const int ks = (tid & 3) * 16;
    unsigned int w[8];
    #pragma unroll
    for (int j = 0; j < 8; ++j)
        w[j] = pk2(t_lds[ks + 2 * j][nl], t_lds[ks + 2 * j + 1][nl]);
    unsigned short* dst = wt + (size_t)which * CC * CC + (size_t)(n0 + nl) * CC + k0 + ks;
    u32x4 o0; o0[0] = w[0]; o0[1] = w[1]; o0[2] = w[2]; o0[3] = w[3];
    u32x4 o1; o1[0] = w[4]; o1[1] = w[5]; o1[2] = w[6]; o1[3] = w[7];
    *(u32x4*)dst = o0;
    *(u32x4*)(dst + 8) = o1;
}

// ---------------------------------------------------------------------------
// Kernel 2: QKV MFMA GEMM, m97 main loop + LDS-transposed coalesced epilogue.
//   Q -> qbf [B,H,T,D] bf16, pre-scaled 0.125 ; K -> kbf [B,H,T,D] bf16
//   V -> vtbf [B,H,D,T] bf16 (transposed)
// ---------------------------------------------------------------------------
__global__ __launch_bounds__(256) void gemm_qkv_mfma(
    const unsigned short* __restrict__ xbf, const unsigned short* __restrict__ wt,
    const float* __restrict__ bq, const float* __restrict__ bk, const float* __restrict__ bv,
    unsigned short* __restrict__ qbf, unsigned short* __restrict__ kbf,
    unsigned short* __restrict__ vtbf)
{
    const int tid = threadIdx.x;
    const int m0 = blockIdx.y * 128;
    const int nc0 = blockIdx.x * 128;        // within concat 3072
    const int which = nc0 >> 10;             // 0=q 1=k 2=v
    const int cb = nc0 & 1023;
    const unsigned short* Bt = wt + (size_t)which * CC * CC;
    const float* bias = (which == 0) ? bq : (which == 1) ? bk : bv;

    __shared__ __align__(16) unsigned short lds_a[128][32];  // linear (m97)
    __shared__ __align__(16) unsigned short lds_b[128][32];
    // epilogue transpose buffer: pitch 136 (272 B rows: 16B-aligned, odd*16B
    // bank-group step -> <=2-way conflicts on all access patterns used here)
    __shared__ __align__(16) unsigned short ebuf[128][136];

    const int lane = tid & 63;
    const int wv = tid >> 6;
    const int wm = (wv & 1) * 64;
    const int wn = (wv >> 1) * 64;
    const int fr = lane & 15;
    const int ks = lane >> 4;

    const int lrow = lane >> 2;          // staging row within 16-row segment
    const int lcol = (lane & 3) * 8;     // staging 16B chunk (bf16 elems)

    f32x4 acc[4][4];
    #pragma unroll
    for (int i = 0; i < 4; ++i)
        #pragma unroll
        for (int j = 0; j < 4; ++j) { acc[i][j][0]=0.f; acc[i][j][1]=0.f; acc[i][j][2]=0.f; acc[i][j][3]=0.f; }

    for (int k0 = 0; k0 < CC; k0 += 32) {
        __syncthreads();
        #pragma unroll
        for (int c = 0; c < 2; ++c) {
            const int r0 = (wv * 2 + c) * 16;
            gload_lds16(xbf + (size_t)(m0 + r0 + lrow) * CC + k0 + lcol, &lds_a[r0][0]);
            gload_lds16(Bt  + (size_t)(cb + r0 + lrow) * CC + k0 + lcol, &lds_b[r0][0]);
        }
        __syncthreads();

        bf16x8 af[4], bfv[4];
        #pragma unroll
        for (int i = 0; i < 4; ++i) {
            af[i]  = __builtin_bit_cast(bf16x8, *(const u32x4*)&lds_a[wm + i * 16 + fr][ks * 8]);
            bfv[i] = __builtin_bit_cast(bf16x8, *(const u32x4*)&lds_b[wn + i * 16 + fr][ks * 8]);
        }
        #pragma unroll
        for (int mi = 0; mi < 4; ++mi)
            #pragma unroll
            for (int ni = 0; ni < 4; ++ni)
                acc[mi][ni] = __builtin_amdgcn_mfma_f32_16x16x32_bf16(af[mi], bfv[ni], acc[mi][ni], 0, 0, 0);
    }

    // ---- epilogue: stage through ebuf, then fully-coalesced 16B stores ----
    // C-frag layout (HW-verified r4/r5): m = wm+mi*16+ks*4+j ; c = wn+ni*16+fr
    if (which != 2) {
        const float scl = (which == 0) ? 0.125f : 1.0f;
        #pragma unroll
        for (int ni = 0; ni < 4; ++ni) {
            const int c_l = wn + ni * 16 + fr;
            const float bv2 = bias[cb + c_l];
            #pragma unroll
            for (int mi = 0; mi < 4; ++mi)
                #pragma unroll
                for (int j = 0; j < 4; ++j)
                    ebuf[wm + mi * 16 + ks * 4 + j][c_l] = f2bf((acc[mi][ni][j] + bv2) * scl);
        }
        __syncthreads();
        unsigned short* dst = (which == 0) ? qbf : kbf;
        #pragma unroll
        for (int p = 0; p < 8; ++p) {
            const int chunk = tid + p * 256;       // 0..2047
            const int m_l = chunk >> 4;            // 0..127
            const int c_l8 = (chunk & 15) * 8;     // 0..120
            const int m = m0 + m_l;
            const int b = m >> 11, t = m & 2047;
            const int c = cb + c_l8;
            const int h = c >> 6, d = c & 63;
            *(u32x4*)(dst + (((size_t)(b * HH + h) * TT + t) * DD) + d) =
                *(const u32x4*)&ebuf[m_l][c_l8];
        }
    } else {
        // V: stage transposed ebuf[c][m], then coalesced along t
        #pragma unroll
        for (int ni = 0; ni < 4; ++ni) {
            const int c_l = wn + ni * 16 + fr;
            const float bv2 = bias[cb + c_l];
            #pragma unroll
            for (int mi = 0; mi < 4; ++mi) {
                const int m_l = wm + mi * 16 + ks * 4;
                unsigned int* q2 = (unsigned int*)&ebuf[c_l][m_l];
                q2[0] = pk2(acc[mi][ni][0] + bv2, acc[mi][ni][1] + bv2);
                q2[1] = pk2(acc[mi][ni][2] + bv2, acc[mi][ni][3] + bv2);
            }
        }
        __syncthreads();
        #pragma unroll
        for (int p = 0; p < 8; ++p) {
            const int chunk = tid + p * 256;
            const int c_l = chunk >> 4;            // 0..127
            const int t_l8 = (chunk & 15) * 8;     // 0..120
            const int c = cb + c_l;
            const int h = c >> 6, d = c & 63;
            const int b = m0 >> 11, t = (m0 & 2047) + t_l8;
            *(u32x4*)(vtbf + ((size_t)(b * HH + h) * DD + d) * TT + t) =
                *(const u32x4*)&ebuf[c_l][t_l8];
        }
    }
}

// ---------------------------------------------------------------------------
// Kernel 3: causal flash attention on MFMA. 512 thr = 8 waves; 128 q-rows
// per block; KVBLK=64; reg-prefetch of next K/V tile. (unchanged from R7)
// ---------------------------------------------------------------------------
__global__ __launch_bounds__(512) void attn_mfma(
    const unsigned short* __restrict__ qbf, const unsigned short* __restrict__ kbf,
    const unsigned short* __restrict__ vtbf, unsigned short* __restrict__ ybf)
{
    const int tid  = threadIdx.x;
    const int w    = tid >> 6;     // 0..7
    const int lane = tid & 63;
    const int g    = lane >> 4;    // 0..3
    const int i    = lane & 15;    // 0..15
    const int qi   = 15 - (int)blockIdx.x;   // heavy tiles first
    const int h    = blockIdx.y;
    const int b    = blockIdx.z;
    const int q0   = qi * 128;
    const size_t hq = (size_t)(b * HH + h) * TT * DD;  // q/k [T][D]
    const size_t hv = (size_t)(b * HH + h) * DD * TT;  // v^T [D][T]

    __shared__ __align__(16) unsigned short k_lds[64][72];
    __shared__ __align__(16) unsigned short vt_lds[64][72];
    __shared__ __align__(16) unsigned short p_lds[128][72];

    bf16x8 qf[2];
    {
        const unsigned short* qrow = qbf + hq + (size_t)(q0 + 16 * w + i) * DD + g * 8;
        qf[0] = __builtin_bit_cast(bf16x8, *(const u32x4*)qrow);
        qf[1] = __builtin_bit_cast(bf16x8, *(const u32x4*)(qrow + 32));
    }

    f32x4 o_acc[4];
    f32x4 m_i, l_i;
    #pragma unroll
    for (int ni = 0; ni < 4; ++ni) { o_acc[ni][0]=0.f; o_acc[ni][1]=0.f; o_acc[ni][2]=0.f; o_acc[ni][3]=0.f; }
    #pragma unroll
    for (int e = 0; e < 4; ++e) { m_i[e] = -1e30f; l_i[e] = 0.f; }

    const int srow  = tid >> 3;         // 0..63
    const int sslot = (tid & 7) * 8;    // bf16 elems

    const int nt = 2 * qi + 2;
    u32x4 kreg = *(const u32x4*)(kbf + hq + (size_t)srow * DD + sslot);
    u32x4 vreg = *(const u32x4*)(vtbf + hv + (size_t)srow * TT + sslot);

    for (int kk = 0; kk < nt; ++kk) {
        __syncthreads();
        *(u32x4*)&k_lds[srow][sslot]  = kreg;
        *(u32x4*)&vt_lds[srow][sslot] = vreg;
        __syncthreads();
        if (kk + 1 < nt) {
            const int s1 = (kk + 1) * 64;
            kreg = *(const u32x4*)(kbf + hq + (size_t)(s1 + srow) * DD + sslot);
            vreg = *(const u32x4*)(vtbf + hv + (size_t)srow * TT + s1 + sslot);
        }

        if (kk == nt - 1 && w < 4) continue;

        const int s0 = kk * 64;
        f32x4 s_acc[4];
        #pragma unroll
        for (int ni = 0; ni < 4; ++ni) { s_acc[ni][0]=0.f; s_acc[ni][1]=0.f; s_acc[ni][2]=0.f; s_acc[ni][3]=0.f; }
        #pragma unroll
        for (int lks = 0; lks < 2; ++lks)
            #pragma unroll
            for (int ni = 0; ni < 4; ++ni) {
                bf16x8 kb = __builtin_bit_cast(bf16x8,
                    *(const u32x4*)&k_lds[ni * 16 + i][lks * 32 + g * 8]);
                s_acc[ni] = __builtin_amdgcn_mfma_f32_16x16x32_bf16(qf[lks], kb, s_acc[ni], 0, 0, 0);
            }

        if (kk >= 2 * qi) {
            const int r_glob = q0 + 16 * w + 4 * g;
            #pragma unroll
            for (int ni = 0; ni < 4; ++ni) {
                const int s_glob = s0 + ni * 16 + i;
                #pragma unroll
                for (int reg = 0; reg < 4; ++reg)
                    if (s_glob > r_glob + reg) s_acc[ni][reg] = -1e30f;
            }
        }

        f32x4 rmax = s_acc[0];
        #pragma unroll
        for (int ni = 1; ni < 4; ++ni)
            #pragma unroll
            for (int e = 0; e < 4; ++e) rmax[e] = fmaxf(rmax[e], s_acc[ni][e]);
        #pragma unroll
        for (int msk = 1; msk < 16; msk <<= 1)
            #pragma unroll
            for (int e = 0; e < 4; ++e) rmax[e] = fmaxf(rmax[e], __shfl_xor(rmax[e], msk));

        f32x4 m_new, alpha;
        #pragma unroll
        for (int e = 0; e < 4; ++e) {
            m_new[e] = fmaxf(m_i[e], rmax[e]);
            alpha[e] = __expf(m_i[e] - m_new[e]);
        }
        f32x4 rsum;
        #pragma unroll
        for (int e = 0; e < 4; ++e) rsum[e] = 0.f;
        #pragma unroll
        for (int ni = 0; ni < 4; ++ni)
            #pragma unroll
            for (int e = 0; e < 4; ++e) {
                float pv = __expf(s_acc[ni][e] - m_new[e]);
                s_acc[ni][e] = pv;
                rsum[e] += pv;
            }
        #pragma unroll
        for (int msk = 1; msk < 16; msk <<= 1)
            #pragma unroll
            for (int e = 0; e < 4; ++e) rsum[e] += __shfl_xor(rsum[e], msk);
        #pragma unroll
        for (int e = 0; e < 4; ++e) {
            l_i[e] = l_i[e] * alpha[e] + rsum[e];
            m_i[e] = m_new[e];
        }
        #pragma unroll
        for (int ni = 0; ni < 4; ++ni)
            #pragma unroll
            for (int e = 0; e < 4; ++e) o_acc[ni][e] *= alpha[e];

        #pragma unroll
        for (int ni = 0; ni < 4; ++ni)
            #pragma unroll
            for (int reg = 0; reg < 4; ++reg)
                p_lds[16 * w + 4 * g + reg][ni * 16 + i] = f2bf(s_acc[ni][reg]);

        #pragma unroll
        for (int lks = 0; lks < 2; ++lks) {
            bf16x8 pa = __builtin_bit_cast(bf16x8,
                *(const u32x4*)&p_lds[16 * w + i][lks * 32 + g * 8]);
            #pragma unroll
            for (int ni = 0; ni < 4; ++ni) {
                bf16x8 vb = __builtin_bit_cast(bf16x8,
                    *(const u32x4*)&vt_lds[ni * 16 + i][lks * 32 + g * 8]);
                o_acc[ni] = __builtin_amdgcn_mfma_f32_16x16x32_bf16(pa, vb, o_acc[ni], 0, 0, 0);
            }
        }
    }

    f32x4 inv;
    #pragma unroll
    for (int e = 0; e < 4; ++e) inv[e] = 1.0f / l_i[e];
    #pragma unroll
    for (int ni = 0; ni < 4; ++ni)
        #pragma unroll
        for (int reg = 0; reg < 4; ++reg)
            ybf[((size_t)b * TT + (q0 + 16 * w + 4 * g + reg)) * CC + h * DD + ni * 16 + i] =
                f2bf(o_acc[ni][reg] * inv[reg]);
}

// ---------------------------------------------------------------------------
// Kernel 4: out-proj MFMA GEMM (m97 structure). out = y_bf @ Wo^T + bo, fp32.
// ---------------------------------------------------------------------------
__global__ __launch_bounds__(256) void gemm_out_mfma(
    const unsigned short* __restrict__ ybf, const unsigned short* __restrict__ wt_o,
    const float* __restrict__ bo, float* __restrict__ out)
{
    const int tid = threadIdx.x;
    const int m0 = blockIdx.y * 128;
    const int n0 = blockIdx.x * 128;

    __shared__ __align__(16) unsigned short lds_a[128][32];
    __shared__ __align__(16) unsigned short lds_b[128][32];

    const int lane = tid & 63;
    const int wv = tid >> 6;
    const int wm = (wv & 1) * 64;
    const int wn = (wv >> 1) * 64;
    const int fr = lane & 15;
    const int ks = lane >> 4;
    const int lrow = lane >> 2;
    const int lcol = (lane & 3) * 8;

    f32x4 acc[4][4];
    #pragma unroll
    for (int i = 0; i < 4; ++i)
        #pragma unroll
        for (int j = 0; j < 4; ++j) { acc[i][j][0]=0.f; acc[i][j][1]=0.f; acc[i][j][2]=0.f; acc[i][j][3]=0.f; }

    for (int k0 = 0; k0 < CC; k0 += 32) {
        __syncthreads();
        #pragma unroll
        for (int c = 0; c < 2; ++c) {
            const int r0 = (wv * 2 + c) * 16;
            gload_lds16(ybf  + (size_t)(m0 + r0 + lrow) * CC + k0 + lcol, &lds_a[r0][0]);
            gload_lds16(wt_o + (size_t)(n0 + r0 + lrow) * CC + k0 + lcol, &lds_b[r0][0]);
        }
        __syncthreads();

        bf16x8 af[4], bfv[4];
        #pragma unroll
        for (int i = 0; i < 4; ++i) {
            af[i]  = __builtin_bit_cast(bf16x8, *(const u32x4*)&lds_a[wm + i * 16 + fr][ks * 8]);
            bfv[i] = __builtin_bit_cast(bf16x8, *(const u32x4*)&lds_b[wn + i * 16 + fr][ks * 8]);
        }
        #pragma unroll
        for (int mi = 0; mi < 4; ++mi)
            #pragma unroll
            for (int ni = 0; ni < 4; ++ni)
                acc[mi][ni] = __builtin_amdgcn_mfma_f32_16x16x32_bf16(af[mi], bfv[ni], acc[mi][ni], 0, 0, 0);
    }

    #pragma unroll
    for (int ni = 0; ni < 4; ++ni) {
        const int n = n0 + wn + ni * 16 + fr;
        const float bv2 = bo[n];
        #pragma unroll
        for (int mi = 0; mi < 4; ++mi) {
            #pragma unroll
            for (int j = 0; j < 4; ++j) {
                const int m = m0 + wm + mi * 16 + ks * 4 + j;
                out[(size_t)m * CC + n] = acc[mi][ni][j] + bv2;
            }
        }
    }
}

// ---------------------------------------------------------------------------
extern "C" void kernel_launch(void* const* d_in, const int* in_sizes, int n_in,
                              void* d_out, int out_size, void* d_ws, size_t ws_size,
                              hipStream_t stream) {
    const float* x  = (const float*)d_in[0];
    // d_in[1] = mask (bool) — causal structure known, ignored
    const float* Wq = (const float*)d_in[2];
    const float* bq = (const float*)d_in[3];
    const float* Wk = (const float*)d_in[4];
    const float* bk = (const float*)d_in[5];
    const float* Wv = (const float*)d_in[6];
    const float* bv = (const float*)d_in[7];
    const float* Wo = (const float*)d_in[8];
    const float* bo = (const float*)d_in[9];
    float* out = (float*)d_out;

    const size_t NE = (size_t)MM * CC;            // 4,194,304
    unsigned short* xbf  = (unsigned short*)d_ws; // bf16 x
    unsigned short* ybf  = xbf + NE;              // bf16 attn out [B,T,C]
    unsigned short* wt   = ybf + NE;              // 4x 1024x1024 bf16 W^T
    unsigned short* qbf  = wt + (size_t)4 * CC * CC;
    unsigned short* kbf  = qbf + NE;
    unsigned short* vtbf = kbf + NE;

    cvt_f32_bf16<<<2048, 256, 0, stream>>>(x, xbf);
    wtrans_kernel<<<dim3(16, 16, 4), 256, 0, stream>>>(Wq, Wk, Wv, Wo, wt);
    gemm_qkv_mfma<<<dim3(24, 32), 256, 0, stream>>>(
        xbf, wt, bq, bk, bv, qbf, kbf, vtbf);
    attn_mfma<<<dim3(TT / 128, HH, BB), 512, 0, stream>>>(qbf, kbf, vtbf, ybf);
    gemm_out_mfma<<<dim3(8, 32), 256, 0, stream>>>(
        ybf, wt + (size_t)3 * CC * CC, bo, out);
}

// Round 10
// 248.030 us; speedup vs baseline: 4.2209x; 1.0948x over previous
//
#include <hip/hip_runtime.h>
#include <hip/hip_bf16.h>

// Problem constants: B=2, T=2048, C=1024, H=16, D=64
#define BB 2
#define TT 2048
#define CC 1024
#define HH 16
#define DD 64
#define MM (BB*TT)   // 4096

typedef float f32x4 __attribute__((ext_vector_type(4)));
typedef __bf16 bf16x8 __attribute__((ext_vector_type(8)));
typedef unsigned int u32x4 __attribute__((ext_vector_type(4)));
typedef unsigned int u32x2 __attribute__((ext_vector_type(2)));

__device__ __forceinline__ unsigned short f2bf(float f) {
    unsigned int u = __float_as_uint(f);
    u += 0x7fff + ((u >> 16) & 1);          // round-to-nearest-even
    return (unsigned short)(u >> 16);
}
__device__ __forceinline__ unsigned int pk2(float a, float b) {
    return (unsigned int)f2bf(a) | ((unsigned int)f2bf(b) << 16);
}

// global -> LDS direct 16B copy (wave-uniform LDS base + lane*16).
__device__ __forceinline__ void gload_lds16(const void* g, void* l) {
    __builtin_amdgcn_global_load_lds(
        (const __attribute__((address_space(1))) unsigned int*)(unsigned long long)g,
        (__attribute__((address_space(3))) unsigned int*)(unsigned int)(unsigned long long)l,
        16, 0, 0);
}

// ---------------------------------------------------------------------------
// Kernel 0: fp32 -> bf16 elementwise (x). 8 elems/thread, exact cover.
// ---------------------------------------------------------------------------
__global__ __launch_bounds__(256) void cvt_f32_bf16(
    const float* __restrict__ in, unsigned short* __restrict__ out)
{
    const size_t i = (size_t)blockIdx.x * 256 + threadIdx.x;  // unit of 8 elems
    const float4* in4 = (const float4*)in;
    float4 a = in4[2 * i], b = in4[2 * i + 1];
    u32x4 o;
    o[0] = pk2(a.x, a.y); o[1] = pk2(a.z, a.w);
    o[2] = pk2(b.x, b.y); o[3] = pk2(b.z, b.w);
    *(u32x4*)(out + 8 * i) = o;
}

// ---------------------------------------------------------------------------
// Kernel 1: W [1024(k)][1024(n)] fp32 -> W_t bf16 [1024(n)][1024(k)].
// ---------------------------------------------------------------------------
__global__ __launch_bounds__(256) void wtrans_kernel(
    const float* __restrict__ W0, const float* __restrict__ W1,
    const float* __restrict__ W2, const float* __restrict__ W3,
    unsigned short* __restrict__ wt)
{
    const int tid = threadIdx.x;
    const int n0 = blockIdx.x * 64;
    const int k0 = blockIdx.y * 64;
    const int which = blockIdx.z;
    const float* W = (which == 0) ? W0 : (which == 1) ? W1 : (which == 2) ? W2 : W3;

    __shared__ float t_lds[64][68];

    #pragma unroll
    for (int p = 0; p < 4; ++p) {
        int idx = tid + p * 256;
        int r   = idx >> 4;
        int c4  = (idx & 15) * 4;
        *(float4*)&t_lds[r][c4] = *(const float4*)(W + (size_t)(k0 + r) * CC + n0 + c4);
    }
    __syncthreads();

    const int nl = tid >> 2;
    const int ks = (tid & 3) * 16;
    unsigned int w[8];
    #pragma unroll
    for (int j = 0; j < 8; ++j)
        w[j] = pk2(t_lds[ks + 2 * j][nl], t_lds[ks + 2 * j + 1][nl]);
    unsigned short* dst = wt + (size_t)which * CC * CC + (size_t)(n0 + nl) * CC + k0 + ks;
    u32x4 o0; o0[0] = w[0]; o0[1] = w[1]; o0[2] = w[2]; o0[3] = w[3];
    u32x4 o1; o1[0] = w[4]; o1[1] = w[5]; o1[2] = w[6]; o1[3] = w[7];
    *(u32x4*)dst = o0;
    *(u32x4*)(dst + 8) = o1;
}

// ---------------------------------------------------------------------------
// Kernel 2: QKV MFMA GEMM, m97 main loop + LDS-transposed coalesced epilogue.
// (byte-identical to round 8)
// ---------------------------------------------------------------------------
__global__ __launch_bounds__(256) void gemm_qkv_mfma(
    const unsigned short* __restrict__ xbf, const unsigned short* __restrict__ wt,
    const float* __restrict__ bq, const float* __restrict__ bk, const float* __restrict__ bv,
    unsigned short* __restrict__ qbf, unsigned short* __restrict__ kbf,
    unsigned short* __restrict__ vtbf)
{
    const int tid = threadIdx.x;
    const int m0 = blockIdx.y * 128;
    const int nc0 = blockIdx.x * 128;        // within concat 3072
    const int which = nc0 >> 10;             // 0=q 1=k 2=v
    const int cb = nc0 & 1023;
    const unsigned short* Bt = wt + (size_t)which * CC * CC;
    const float* bias = (which == 0) ? bq : (which == 1) ? bk : bv;

    __shared__ __align__(16) unsigned short lds_a[128][32];  // linear (m97)
    __shared__ __align__(16) unsigned short lds_b[128][32];
    __shared__ __align__(16) unsigned short ebuf[128][136];

    const int lane = tid & 63;
    const int wv = tid >> 6;
    const int wm = (wv & 1) * 64;
    const int wn = (wv >> 1) * 64;
    const int fr = lane & 15;
    const int ks = lane >> 4;

    const int lrow = lane >> 2;
    const int lcol = (lane & 3) * 8;

    f32x4 acc[4][4];
    #pragma unroll
    for (int i = 0; i < 4; ++i)
        #pragma unroll
        for (int j = 0; j < 4; ++j) { acc[i][j][0]=0.f; acc[i][j][1]=0.f; acc[i][j][2]=0.f; acc[i][j][3]=0.f; }

    for (int k0 = 0; k0 < CC; k0 += 32) {
        __syncthreads();
        #pragma unroll
        for (int c = 0; c < 2; ++c) {
            const int r0 = (wv * 2 + c) * 16;
            gload_lds16(xbf + (size_t)(m0 + r0 + lrow) * CC + k0 + lcol, &lds_a[r0][0]);
            gload_lds16(Bt  + (size_t)(cb + r0 + lrow) * CC + k0 + lcol, &lds_b[r0][0]);
        }
        __syncthreads();

        bf16x8 af[4], bfv[4];
        #pragma unroll
        for (int i = 0; i < 4; ++i) {
            af[i]  = __builtin_bit_cast(bf16x8, *(const u32x4*)&lds_a[wm + i * 16 + fr][ks * 8]);
            bfv[i] = __builtin_bit_cast(bf16x8, *(const u32x4*)&lds_b[wn + i * 16 + fr][ks * 8]);
        }
        #pragma unroll
        for (int mi = 0; mi < 4; ++mi)
            #pragma unroll
            for (int ni = 0; ni < 4; ++ni)
                acc[mi][ni] = __builtin_amdgcn_mfma_f32_16x16x32_bf16(af[mi], bfv[ni], acc[mi][ni], 0, 0, 0);
    }

    if (which != 2) {
        const float scl = (which == 0) ? 0.125f : 1.0f;
        #pragma unroll
        for (int ni = 0; ni < 4; ++ni) {
            const int c_l = wn + ni * 16 + fr;
            const float bv2 = bias[cb + c_l];
            #pragma unroll
            for (int mi = 0; mi < 4; ++mi)
                #pragma unroll
                for (int j = 0; j < 4; ++j)
                    ebuf[wm + mi * 16 + ks * 4 + j][c_l] = f2bf((acc[mi][ni][j] + bv2) * scl);
        }
        __syncthreads();
        unsigned short* dst = (which == 0) ? qbf : kbf;
        #pragma unroll
        for (int p = 0; p < 8; ++p) {
            const int chunk = tid + p * 256;
            const int m_l = chunk >> 4;
            const int c_l8 = (chunk & 15) * 8;
            const int m = m0 + m_l;
            const int b = m >> 11, t = m & 2047;
            const int c = cb + c_l8;
            const int h = c >> 6, d = c & 63;
            *(u32x4*)(dst + (((size_t)(b * HH + h) * TT + t) * DD) + d) =
                *(const u32x4*)&ebuf[m_l][c_l8];
        }
    } else {
        #pragma unroll
        for (int ni = 0; ni < 4; ++ni) {
            const int c_l = wn + ni * 16 + fr;
            const float bv2 = bias[cb + c_l];
            #pragma unroll
            for (int mi = 0; mi < 4; ++mi) {
                const int m_l = wm + mi * 16 + ks * 4;
                unsigned int* q2 = (unsigned int*)&ebuf[c_l][m_l];
                q2[0] = pk2(acc[mi][ni][0] + bv2, acc[mi][ni][1] + bv2);
                q2[1] = pk2(acc[mi][ni][2] + bv2, acc[mi][ni][3] + bv2);
            }
        }
        __syncthreads();
        #pragma unroll
        for (int p = 0; p < 8; ++p) {
            const int chunk = tid + p * 256;
            const int c_l = chunk >> 4;
            const int t_l8 = (chunk & 15) * 8;
            const int c = cb + c_l;
            const int h = c >> 6, d = c & 63;
            const int b = m0 >> 11, t = (m0 & 2047) + t_l8;
            *(u32x4*)(vtbf + ((size_t)(b * HH + h) * DD + d) * TT + t) =
                *(const u32x4*)&ebuf[c_l][t_l8];
        }
    }
}

// ---------------------------------------------------------------------------
// Kernel 3: causal flash attention, swapped-operand MFMA form.
// 256 thr = 4 waves; 64 q-rows/block (wave w owns rows 16w..16w+15, its
// lane i handles q-row 16w+i). QK^T computed as S^T = mfma(K_frag, Q_frag):
// C-layout puts q in col=lane&15 -> softmax state (m,l,alpha) is LANE-SCALAR;
// row-reduce = 15 in-lane ops + 2 shfl_xor (16,32). PV: O^T = mfma(V^T, P^T).
// Fragment mappings identical to the HW-verified GEMM conventions.
// ---------------------------------------------------------------------------
__global__ __launch_bounds__(256) void attn_mfma(
    const unsigned short* __restrict__ qbf, const unsigned short* __restrict__ kbf,
    const unsigned short* __restrict__ vtbf, unsigned short* __restrict__ ybf)
{
    const int tid  = threadIdx.x;
    const int w    = tid >> 6;     // 0..3
    const int lane = tid & 63;
    const int g    = lane >> 4;    // 0..3
    const int i    = lane & 15;    // 0..15
    const int qi   = 31 - (int)blockIdx.x;   // heavy tiles first
    const int h    = blockIdx.y;
    const int bb   = blockIdx.z;
    const int q0   = qi * 64;
    const size_t hq = (size_t)(bb * HH + h) * TT * DD;  // q/k [T][D]
    const size_t hv = (size_t)(bb * HH + h) * DD * TT;  // v^T [D][T]

    __shared__ __align__(16) unsigned short k_lds[64][72];
    __shared__ __align__(16) unsigned short vt_lds[64][72];
    __shared__ __align__(16) unsigned short p_lds[64][72];

    // Q as B-frag: col=i -> q row q0+16w+i ; k(=d) = lks*32 + g*8 + j
    bf16x8 qf[2];
    {
        const unsigned short* qrow = qbf + hq + (size_t)(q0 + 16 * w + i) * DD + g * 8;
        qf[0] = __builtin_bit_cast(bf16x8, *(const u32x4*)qrow);
        qf[1] = __builtin_bit_cast(bf16x8, *(const u32x4*)(qrow + 32));
    }

    // O^T accum: oT[ni][reg] = O^T[d = ni*16+4g+reg][q = q0+16w+i]
    f32x4 oT[4];
    #pragma unroll
    for (int ni = 0; ni < 4; ++ni) { oT[ni][0]=0.f; oT[ni][1]=0.f; oT[ni][2]=0.f; oT[ni][3]=0.f; }
    float m_i = -1e30f, l_i = 0.0f;

    // staging: 256 threads, 2x 16B chunks per matrix per tile
    const int srow = tid >> 2;          // 0..63
    const int sc0  = (tid & 3) * 8;     // elems; chunks at sc0 and sc0+32

    const int nt = qi + 1;
    u32x4 kreg0 = *(const u32x4*)(kbf + hq + (size_t)srow * DD + sc0);
    u32x4 kreg1 = *(const u32x4*)(kbf + hq + (size_t)srow * DD + sc0 + 32);
    u32x4 vreg0 = *(const u32x4*)(vtbf + hv + (size_t)srow * TT + sc0);
    u32x4 vreg1 = *(const u32x4*)(vtbf + hv + (size_t)srow * TT + sc0 + 32);

    for (int kk = 0; kk < nt; ++kk) {
        __syncthreads();   // prev tile's LDS fully consumed
        *(u32x4*)&k_lds[srow][sc0]       = kreg0;
        *(u32x4*)&k_lds[srow][sc0 + 32]  = kreg1;
        *(u32x4*)&vt_lds[srow][sc0]      = vreg0;
        *(u32x4*)&vt_lds[srow][sc0 + 32] = vreg1;
        __syncthreads();
        if (kk + 1 < nt) {   // prefetch next tile; latency hides under compute
            const int s1 = (kk + 1) * 64;
            kreg0 = *(const u32x4*)(kbf + hq + (size_t)(s1 + srow) * DD + sc0);
            kreg1 = *(const u32x4*)(kbf + hq + (size_t)(s1 + srow) * DD + sc0 + 32);
            vreg0 = *(const u32x4*)(vtbf + hv + (size_t)srow * TT + s1 + sc0);
            vreg1 = *(const u32x4*)(vtbf + hv + (size_t)srow * TT + s1 + sc0 + 32);
        }

        // S^T = K Q^T : sT[ni][reg] = S[s = ni*16+4g+reg][q = 16w+i]
        f32x4 sT[4];
        #pragma unroll
        for (int ni = 0; ni < 4; ++ni) { sT[ni][0]=0.f; sT[ni][1]=0.f; sT[ni][2]=0.f; sT[ni][3]=0.f; }
        #pragma unroll
        for (int lks = 0; lks < 2; ++lks)
            #pragma unroll
            for (int ni = 0; ni < 4; ++ni) {
                bf16x8 ka = __builtin_bit_cast(bf16x8,
                    *(const u32x4*)&k_lds[ni * 16 + i][lks * 32 + g * 8]);
                sT[ni] = __builtin_amdgcn_mfma_f32_16x16x32_bf16(ka, qf[lks], sT[ni], 0, 0, 0);
            }

        if (kk == qi) {   // diagonal tile (s0 == q0): mask s_local > q_local
            const int q_l = 16 * w + i;
            #pragma unroll
            for (int ni = 0; ni < 4; ++ni)
                #pragma unroll
                for (int reg = 0; reg < 4; ++reg)
                    if (ni * 16 + 4 * g + reg > q_l) sT[ni][reg] = -1e30f;
        }

        // --- lane-scalar online softmax (q = lane's column) ---
        float tmax = sT[0][0];
        #pragma unroll
        for (int ni = 0; ni < 4; ++ni)
            #pragma unroll
            for (int e = 0; e < 4; ++e) tmax = fmaxf(tmax, sT[ni][e]);
        tmax = fmaxf(tmax, __shfl_xor(tmax, 16));
        tmax = fmaxf(tmax, __shfl_xor(tmax, 32));
        const float m_new = fmaxf(m_i, tmax);
        const float alpha = __expf(m_i - m_new);
        float lsum = 0.f;
        #pragma unroll
        for (int ni = 0; ni < 4; ++ni)
            #pragma unroll
            for (int e = 0; e < 4; ++e) {
                float pv = __expf(sT[ni][e] - m_new);
                sT[ni][e] = pv;
                lsum += pv;
            }
        lsum += __shfl_xor(lsum, 16);
        lsum += __shfl_xor(lsum, 32);
        l_i = l_i * alpha + lsum;
        m_i = m_new;
        #pragma unroll
        for (int ni = 0; ni < 4; ++ni)
            #pragma unroll
            for (int e = 0; e < 4; ++e) oT[ni][e] *= alpha;

        // P -> p_lds[q_local][s] as bf16, 8B stores (4 consecutive s per store)
        #pragma unroll
        for (int ni = 0; ni < 4; ++ni) {
            u32x2 pr;
            pr[0] = pk2(sT[ni][0], sT[ni][1]);
            pr[1] = pk2(sT[ni][2], sT[ni][3]);
            *(u32x2*)&p_lds[16 * w + i][ni * 16 + 4 * g] = pr;
        }

        // O^T += V^T P^T : A = V^T rows(d), B col=q=i, k=s
        #pragma unroll
        for (int lks = 0; lks < 2; ++lks) {
            bf16x8 pb = __builtin_bit_cast(bf16x8,
                *(const u32x4*)&p_lds[16 * w + i][lks * 32 + g * 8]);
            #pragma unroll
            for (int ni = 0; ni < 4; ++ni) {
                bf16x8 va = __builtin_bit_cast(bf16x8,
                    *(const u32x4*)&vt_lds[ni * 16 + i][lks * 32 + g * 8]);
                oT[ni] = __builtin_amdgcn_mfma_f32_16x16x32_bf16(va, pb, oT[ni], 0, 0, 0);
            }
        }
    }

    // Finalize: lane holds O^T[d=ni*16+4g+reg][q=q0+16w+i]; d consecutive in reg
    const float inv = 1.0f / l_i;
    unsigned short* ybase = ybf + ((size_t)bb * TT + (q0 + 16 * w + i)) * CC + h * DD;
    #pragma unroll
    for (int ni = 0; ni < 4; ++ni) {
        u32x2 st;
        st[0] = pk2(oT[ni][0] * inv, oT[ni][1] * inv);
        st[1] = pk2(oT[ni][2] * inv, oT[ni][3] * inv);
        *(u32x2*)(ybase + ni * 16 + 4 * g) = st;
    }
}

// ---------------------------------------------------------------------------
// Kernel 4: out-proj MFMA GEMM (m97 structure). out = y_bf @ Wo^T + bo, fp32.
// (byte-identical to round 8)
// ---------------------------------------------------------------------------
__global__ __launch_bounds__(256) void gemm_out_mfma(
    const unsigned short* __restrict__ ybf, const unsigned short* __restrict__ wt_o,
    const float* __restrict__ bo, float* __restrict__ out)
{
    const int tid = threadIdx.x;
    const int m0 = blockIdx.y * 128;
    const int n0 = blockIdx.x * 128;

    __shared__ __align__(16) unsigned short lds_a[128][32];
    __shared__ __align__(16) unsigned short lds_b[128][32];

    const int lane = tid & 63;
    const int wv = tid >> 6;
    const int wm = (wv & 1) * 64;
    const int wn = (wv >> 1) * 64;
    const int fr = lane & 15;
    const int ks = lane >> 4;
    const int lrow = lane >> 2;
    const int lcol = (lane & 3) * 8;

    f32x4 acc[4][4];
    #pragma unroll
    for (int i = 0; i < 4; ++i)
        #pragma unroll
        for (int j = 0; j < 4; ++j) { acc[i][j][0]=0.f; acc[i][j][1]=0.f; acc[i][j][2]=0.f; acc[i][j][3]=0.f; }

    for (int k0 = 0; k0 < CC; k0 += 32) {
        __syncthreads();
        #pragma unroll
        for (int c = 0; c < 2; ++c) {
            const int r0 = (wv * 2 + c) * 16;
            gload_lds16(ybf  + (size_t)(m0 + r0 + lrow) * CC + k0 + lcol, &lds_a[r0][0]);
            gload_lds16(wt_o + (size_t)(n0 + r0 + lrow) * CC + k0 + lcol, &lds_b[r0][0]);
        }
        __syncthreads();

        bf16x8 af[4], bfv[4];
        #pragma unroll
        for (int i = 0; i < 4; ++i) {
            af[i]  = __builtin_bit_cast(bf16x8, *(const u32x4*)&lds_a[wm + i * 16 + fr][ks * 8]);
            bfv[i] = __builtin_bit_cast(bf16x8, *(const u32x4*)&lds_b[wn + i * 16 + fr][ks * 8]);
        }
        #pragma unroll
        for (int mi = 0; mi < 4; ++mi)
            #pragma unroll
            for (int ni = 0; ni < 4; ++ni)
                acc[mi][ni] = __builtin_amdgcn_mfma_f32_16x16x32_bf16(af[mi], bfv[ni], acc[mi][ni], 0, 0, 0);
    }

    #pragma unroll
    for (int ni = 0; ni < 4; ++ni) {
        const int n = n0 + wn + ni * 16 + fr;
        const float bv2 = bo[n];
        #pragma unroll
        for (int mi = 0; mi < 4; ++mi) {
            #pragma unroll
            for (int j = 0; j < 4; ++j) {
                const int m = m0 + wm + mi * 16 + ks * 4 + j;
                out[(size_t)m * CC + n] = acc[mi][ni][j] + bv2;
            }
        }
    }
}

// ---------------------------------------------------------------------------
extern "C" void kernel_launch(void* const* d_in, const int* in_sizes, int n_in,
                              void* d_out, int out_size, void* d_ws, size_t ws_size,
                              hipStream_t stream) {
    const float* x  = (const float*)d_in[0];
    // d_in[1] = mask (bool) — causal structure known, ignored
    const float* Wq = (const float*)d_in[2];
    const float* bq = (const float*)d_in[3];
    const float* Wk = (const float*)d_in[4];
    const float* bk = (const float*)d_in[5];
    const float* Wv = (const float*)d_in[6];
    const float* bv = (const float*)d_in[7];
    const float* Wo = (const float*)d_in[8];
    const float* bo = (const float*)d_in[9];
    float* out = (float*)d_out;

    const size_t NE = (size_t)MM * CC;            // 4,194,304
    unsigned short* xbf  = (unsigned short*)d_ws; // bf16 x
    unsigned short* ybf  = xbf + NE;              // bf16 attn out [B,T,C]
    unsigned short* wt   = ybf + NE;              // 4x 1024x1024 bf16 W^T
    unsigned short* qbf  = wt + (size_t)4 * CC * CC;
    unsigned short* kbf  = qbf + NE;
    unsigned short* vtbf = kbf + NE;

    cvt_f32_bf16<<<2048, 256, 0, stream>>>(x, xbf);
    wtrans_kernel<<<dim3(16, 16, 4), 256, 0, stream>>>(Wq, Wk, Wv, Wo, wt);
    gemm_qkv_mfma<<<dim3(24, 32), 256, 0, stream>>>(
        xbf, wt, bq, bk, bv, qbf, kbf, vtbf);
    attn_mfma<<<dim3(TT / 64, HH, BB), 256, 0, stream>>>(qbf, kbf, vtbf, ybf);
    gemm_out_mfma<<<dim3(8, 32), 256, 0, stream>>>(
        ybf, wt + (size_t)3 * CC * CC, bo, out);
}